// Round 4
// baseline (2045.237 us; speedup 1.0000x reference)
//
#include <hip/hip_runtime.h>
#include <cstdint>
#include <cstddef>

// ---------------- problem constants ----------------
#define BS    4096
#define DIM   768
#define GM    128
#define GN    128
#define COMPS (GM * GN)          // 16384
#define NITER_F 1000.0f
#define ALPHA0  0.3f
#define SIGMA0  64.0f            // max(M,N)/2

typedef _Float16 half8  __attribute__((ext_vector_type(8)));
typedef _Float16 half4v __attribute__((ext_vector_type(4)));
typedef float    floatx4 __attribute__((ext_vector_type(4)));
typedef float    floatx16 __attribute__((ext_vector_type(16)));

// ---------------- workspace layout (bytes) ----------------
// Phase 1 (pre-bmu): xh fp16 @0 (6.3MB), wh fp16 @8MB (25.2MB).
// Phase 2 (post-bmu): G fp32 full-width @0 (50.33MB) — aliases xh/wh (dead).
// H fp16 lives packed INSIDE G's rows (see convA). Tails: best, cnt, wn2.
#define XH_OFF    0UL
#define WH_OFF    (8UL * 1024UL * 1024UL)
#define G_OFF     0UL
#define G_BYTES   ((size_t)COMPS * DIM * 4UL)     // 50,331,648
#define BEST_OFF  G_BYTES
#define BEST_BYTES ((size_t)BS * 8UL)             // 32 KB
#define CNT_OFF   (BEST_OFF + BEST_BYTES)
#define CNT_BYTES ((size_t)COMPS * 4UL)           // 64 KB
#define WN2_OFF   (CNT_OFF + CNT_BYTES)

#define GPTR(p) ((const __attribute__((address_space(1))) void*)(p))
#define LPTR(p) ((__attribute__((address_space(3))) void*)(p))

// pack (score, index) so that u64 max == (max score, min index on ties)
__device__ __forceinline__ unsigned long long packScore(float s, int c) {
    unsigned u = __float_as_uint(s);
    u = (u & 0x80000000u) ? ~u : (u | 0x80000000u);   // order-preserving map
    return ((unsigned long long)u << 32) | (unsigned)(~(unsigned)c);
}

__device__ __forceinline__ unsigned long long shfl_xor_u64(unsigned long long v, int m) {
    unsigned lo = (unsigned)v, hi = (unsigned)(v >> 32);
    lo = (unsigned)__shfl_xor((int)lo, m, 64);
    hi = (unsigned)__shfl_xor((int)hi, m, 64);
    return ((unsigned long long)hi << 32) | lo;
}

// ---------------- fp32 -> fp16 convert (x) ----------------
__global__ void cvt_kernel(const float* __restrict__ src, _Float16* __restrict__ dst, int n4) {
    int i = blockIdx.x * 256 + threadIdx.x;
    if (i >= n4) return;
    float4 v = ((const float4*)src)[i];
    half4v h;
    h[0] = (_Float16)v.x; h[1] = (_Float16)v.y;
    h[2] = (_Float16)v.z; h[3] = (_Float16)v.w;
    ((half4v*)dst)[i] = h;
}

// ---------------- w: fp32->fp16 convert fused with 0.5*||w_c||^2 ----------------
__global__ __launch_bounds__(192) void cvtw_wn2_kernel(
    const float* __restrict__ w, _Float16* __restrict__ wh, float* __restrict__ wn2) {
    const int c = blockIdx.x;
    const int t = threadIdx.x;                   // 0..191 (one float4 each)
    const size_t i4 = (size_t)c * 192 + t;
    float4 v = ((const float4*)w)[i4];
    half4v h;
    h[0] = (_Float16)v.x; h[1] = (_Float16)v.y;
    h[2] = (_Float16)v.z; h[3] = (_Float16)v.w;
    ((half4v*)wh)[i4] = h;
    float s = v.x * v.x + v.y * v.y + v.z * v.z + v.w * v.w;
    #pragma unroll
    for (int off = 32; off; off >>= 1) s += __shfl_down(s, off, 64);
    __shared__ float p[3];
    if ((t & 63) == 0) p[t >> 6] = s;
    __syncthreads();
    if (t == 0) wn2[c] = 0.5f * (p[0] + p[1] + p[2]);
}

// ---------------- MFMA BMU v4: 256x256 tile, BK=32, 32x32x16 MFMA, 2 blocks/CU ----
// best_b = argmax_c (x_b.w_c - 0.5||w_c||^2).
// 8 waves (2M x 4N), per-wave 128x64 output as 4x2 tiles of 32x32 (acc floatx16).
// v4 vs v2/v3: (a) back to v2's single-barrier-per-K-tile loop (v3's phase
// split + lgkmcnt(0) pinning regressed: it defeated the compiler's fine
// lgkmcnt interleave and doubled barriers at 2 waves/SIMD); (b) ring depth
// 4->2 (LDS 128KB->66KB) so TWO blocks co-reside per CU — m114/m97 implicit
// inter-block overlap covers the drain; (c) 32x32x16 MFMA: half the MFMA
// instructions, ~15% higher measured ceiling, same LDS traffic.
// Loop invariants (depth 2):
//  - top of iter t: vmcnt(0) retires stage(t) (issued iter t-1, a full MFMA
//    phase ago); s_barrier makes tile t globally resident.
//  - stage(t+1) -> buf[(t+1)&1] issued after that barrier; all waves' reads
//    of buf[(t+1)&1] (iter t-1) completed before it (lgkmcnt consumed). Safe.
// LDS layout (unchanged): line = row>>1, phys slot = ((row&1)*4|chunk)^(line&7);
// global source pre-swizzled so the linear global_load_lds dest matches.
// Fragment rows start at multiples of 32 -> read lane-groups cover 8 distinct
// slots per 8 lanes -> conflict-free (measured 0 conflicts on v1-v3 scheme).
#define BMU_NT 24   // 768 / 32

__global__ __launch_bounds__(512, 4) void bmu_kernel(
    const _Float16* __restrict__ xh, const _Float16* __restrict__ wh,
    const float* __restrict__ wn2, unsigned long long* __restrict__ best) {
    __shared__ _Float16 AB[2][2][8192];       // [buf][A,B][128 lines x 64 halves] = 64KB
    __shared__ unsigned long long red[256];

    const int tid  = threadIdx.x;
    const int wv   = tid >> 6;
    const int lane = tid & 63;
    const int l31  = lane & 31;
    const int hsel = lane >> 5;      // k-octet selector within K=16
    const int wr   = wv >> 2;        // 0..1 (M half)
    const int wc   = wv & 3;         // 0..3 (N quarter)

    // XCD remap: each XCD owns 8 w-tiles; concurrent window (2 blocks/CU x 32
    // CUs = 64 blocks) = 8 cb x 8 bb -> 6.1MB working set in 4MB L2.
    const int bid = blockIdx.x;      // 0..1023
    const int xcd = bid & 7;
    const int rem = bid >> 3;        // 0..127
    const int cb  = xcd * 8 + (rem & 7);
    const int bb  = ((rem >> 3) & 7) + ((rem >> 6) << 3);
    const int b0 = bb * 256;
    const int c0 = cb * 256;

    if (tid < 256) red[tid] = 0ULL;

    // staging source decomposition (pre-swizzled global addresses) — as v2.
    const int Ls = tid >> 3;         // global line (wv*8 + lane>>3)
    const int ss = tid & 7;          // phys slot == linear dest slot
    const int sl = ss ^ (Ls & 7);    // logical slot
    const int prow = 2 * Ls + (sl >> 2);     // row within 128-row half
    const int kc8  = (sl & 3) * 8;           // k-chunk offset (halves)
    const _Float16* gA0 = xh + (size_t)(b0 + prow) * DIM + kc8;
    const _Float16* gA1 = gA0 + (size_t)128 * DIM;
    const _Float16* gB0 = wh + (size_t)(c0 + prow) * DIM + kc8;
    const _Float16* gB1 = gB0 + (size_t)128 * DIM;
    const int ldsoff = wv * 512;     // halves: wave-uniform base

    // fragment LDS offsets (halves): A 4 mtiles x 2 k-halves, B 2 ntiles x 2
    int aoff[4][2], boff[2][2];
    #pragma unroll
    for (int i = 0; i < 4; ++i)
        #pragma unroll
        for (int h = 0; h < 2; ++h) {
            const int row = wr * 128 + i * 32 + l31;
            const int line = row >> 1;
            const int ck = h * 2 + hsel;
            const int ps = (((row & 1) << 2) | ck) ^ (line & 7);
            aoff[i][h] = line * 64 + ps * 8;
        }
    #pragma unroll
    for (int j = 0; j < 2; ++j)
        #pragma unroll
        for (int h = 0; h < 2; ++h) {
            const int row = wc * 64 + j * 32 + l31;
            const int line = row >> 1;
            const int ck = h * 2 + hsel;
            const int ps = (((row & 1) << 2) | ck) ^ (line & 7);
            boff[j][h] = line * 64 + ps * 8;
        }

    floatx16 acc[4][2];
    #pragma unroll
    for (int i = 0; i < 4; ++i)
        #pragma unroll
        for (int j = 0; j < 2; ++j)
            #pragma unroll
            for (int r = 0; r < 16; ++r) acc[i][j][r] = 0.f;

    // prologue: stage tile 0
    {
        _Float16* A = &AB[0][0][0];
        _Float16* B = &AB[0][1][0];
        __builtin_amdgcn_global_load_lds(GPTR(gA0), LPTR(A + ldsoff),        16, 0, 0);
        __builtin_amdgcn_global_load_lds(GPTR(gA1), LPTR(A + 4096 + ldsoff), 16, 0, 0);
        __builtin_amdgcn_global_load_lds(GPTR(gB0), LPTR(B + ldsoff),        16, 0, 0);
        __builtin_amdgcn_global_load_lds(GPTR(gB1), LPTR(B + 4096 + ldsoff), 16, 0, 0);
    }

    for (int t = 0; t < BMU_NT; ++t) {
        // retire stage(t) (issued a full compute phase ago), then publish
        asm volatile("s_waitcnt vmcnt(0)" ::: "memory");
        __builtin_amdgcn_s_barrier();
        asm volatile("" ::: "memory");   // no LDS-read hoisting above the barrier

        const _Float16* A = &AB[t & 1][0][0];
        const _Float16* B = &AB[t & 1][1][0];

        // issue next-tile stage ASAP (longest-latency ops first)
        if (t + 1 < BMU_NT) {
            _Float16* An = &AB[(t + 1) & 1][0][0];
            _Float16* Bn = &AB[(t + 1) & 1][1][0];
            const int t1 = (t + 1) * 32;
            __builtin_amdgcn_global_load_lds(GPTR(gA0 + t1), LPTR(An + ldsoff),        16, 0, 0);
            __builtin_amdgcn_global_load_lds(GPTR(gA1 + t1), LPTR(An + 4096 + ldsoff), 16, 0, 0);
            __builtin_amdgcn_global_load_lds(GPTR(gB0 + t1), LPTR(Bn + ldsoff),        16, 0, 0);
            __builtin_amdgcn_global_load_lds(GPTR(gB1 + t1), LPTR(Bn + 4096 + ldsoff), 16, 0, 0);
        }

        // fragment reads (compiler interleaves lgkmcnt finely with MFMAs)
        half8 af[4][2], bf[2][2];
        #pragma unroll
        for (int i = 0; i < 4; ++i) {
            af[i][0] = *(const half8*)(A + aoff[i][0]);
            af[i][1] = *(const half8*)(A + aoff[i][1]);
        }
        #pragma unroll
        for (int j = 0; j < 2; ++j) {
            bf[j][0] = *(const half8*)(B + boff[j][0]);
            bf[j][1] = *(const half8*)(B + boff[j][1]);
        }

        __builtin_amdgcn_s_setprio(1);
        #pragma unroll
        for (int h = 0; h < 2; ++h)
            #pragma unroll
            for (int i = 0; i < 4; ++i)
                #pragma unroll
                for (int j = 0; j < 2; ++j)
                    acc[i][j] = __builtin_amdgcn_mfma_f32_32x32x16_f16(af[i][h], bf[j][h], acc[i][j], 0, 0, 0);
        __builtin_amdgcn_s_setprio(0);
    }

    // ---------------- argmax epilogue (32x32 C/D map) ----------------
    // col = lane&31 (c index), row = (r&3) + 8*(r>>2) + 4*(lane>>5) (b index)
    float wnj[2];
    #pragma unroll
    for (int j = 0; j < 2; ++j) wnj[j] = wn2[c0 + wc * 64 + j * 32 + l31];

    #pragma unroll
    for (int i = 0; i < 4; ++i) {
        #pragma unroll
        for (int r = 0; r < 16; ++r) {
            unsigned long long m = 0ULL;
            #pragma unroll
            for (int j = 0; j < 2; ++j) {
                const float s = acc[i][j][r] - wnj[j];
                const unsigned long long p = packScore(s, c0 + wc * 64 + j * 32 + l31);
                if (p > m) m = p;
            }
            #pragma unroll
            for (int msk = 1; msk <= 16; msk <<= 1) {
                const unsigned long long o = shfl_xor_u64(m, msk);
                if (o > m) m = o;
            }
            if (l31 == 0)
                atomicMax(&red[wr * 128 + i * 32 + (r & 3) + 8 * (r >> 2) + 4 * hsel], m);
        }
    }
    __syncthreads();
    if (tid < 256) atomicMax(&best[b0 + tid], red[tid]);
}

// ---------------- scatter x rows into full-width G + histogram ----------------
__global__ void scatter_kernel(const unsigned long long* __restrict__ best,
                               const float* __restrict__ x,
                               float* __restrict__ G, float* __restrict__ cnt) {
    const int b = blockIdx.x;
    const int c = (int)(~(unsigned)(best[b] & 0xFFFFFFFFULL));
    float* gr = G + (size_t)c * DIM;
    const float* xr = x + (size_t)b * DIM;
    #pragma unroll
    for (int u = 0; u < 3; ++u) {
        const int d = threadIdx.x + u * 256;
        atomicAdd(&gr[d], xr[d]);
    }
    if (threadIdx.x == 0) atomicAdd(&cnt[c], 1.0f);
}

#define EP 136   // Es pitch (halves)
#define BP 40    // Bs pitch (halves)

// ---- conv pass A (MFMA): H[(i,jc), d] = sum_j E[jc,j] * G[(i,j), d]; H fp16 packed into G rows ----
__global__ __launch_bounds__(256) void convA_kernel(
    const float* G, _Float16* Hh, const int* __restrict__ itp) {
    __shared__ _Float16 Es[128 * EP];   // E fp16, later reused as fp32 bounce
    __shared__ _Float16 Bs[128 * BP];
    const int d0 = blockIdx.x * 128;    // 0..5
    const int ib = blockIdx.y;          // 0..127
    const int tid = threadIdx.x;
    const int wv = tid >> 6, lane = tid & 63;
    const int l15 = lane & 15, q = lane >> 4;
    const int mrow = (wv >> 1) * 64, ncol = (wv & 1) * 64;

    {   // compute E tile in LDS on the fly
        const float decay = 1.f - (float)(*itp) / NITER_F;
        const float sig = SIGMA0 * decay;
        const float inv = -1.f / (sig * sig);
        const int row = tid >> 1, hh = tid & 1;
        _Float16* dst = Es + row * EP + hh * 64;
        #pragma unroll
        for (int u = 0; u < 64; ++u) {
            const float dd = (float)(row - hh * 64 - u);
            dst[u] = (_Float16)__expf(dd * dd * inv);
        }
    }

    floatx4 acc[4][4];
    #pragma unroll
    for (int i = 0; i < 4; ++i)
        #pragma unroll
        for (int j = 0; j < 4; ++j) acc[i][j] = (floatx4){0.f, 0.f, 0.f, 0.f};

    const int dpo = (tid & 15) * 8;     // d-octet within 128
    const int rsel = tid >> 4;          // 0..15 row selector
    for (int k0 = 0; k0 < 128; k0 += 32) {
        __syncthreads();
        #pragma unroll
        for (int s = 0; s < 2; ++s) {   // coalesced: 16 lanes read one row's 512B
            const int j = k0 + s * 16 + rsel;
            const float* r = G + (size_t)(ib * 128 + j) * DIM + d0 + dpo;
            float4 a0 = *(const float4*)r, a1 = *(const float4*)(r + 4);
            float va[8] = {a0.x, a0.y, a0.z, a0.w, a1.x, a1.y, a1.z, a1.w};
            #pragma unroll
            for (int u = 0; u < 8; ++u)
                Bs[(dpo + u) * BP + (s * 16 + rsel)] = (_Float16)va[u];
        }
        __syncthreads();
        half8 af[4], bf[4];
        #pragma unroll
        for (int i = 0; i < 4; ++i)
            af[i] = *(const half8*)(Es + (mrow + i * 16 + l15) * EP + k0 + q * 8);
        #pragma unroll
        for (int j = 0; j < 4; ++j)
            bf[j] = *(const half8*)(Bs + (ncol + j * 16 + l15) * BP + q * 8);
        #pragma unroll
        for (int i = 0; i < 4; ++i)
            #pragma unroll
            for (int j = 0; j < 4; ++j)
                acc[i][j] = __builtin_amdgcn_mfma_f32_16x16x32_f16(af[i], bf[j], acc[i][j], 0, 0, 0);
    }
    __syncthreads();
    // fp32 bounce epilogue in 2 chunks of 64 rows (m = jc), write H fp16 chunk-packed
    float* Ebf = (float*)Es;            // [64][132] floats = 33792 B <= 34816
    #pragma unroll
    for (int ch = 0; ch < 2; ++ch) {
        if ((wv >> 1) == ch) {
            #pragma unroll
            for (int i = 0; i < 4; ++i)
                #pragma unroll
                for (int j = 0; j < 4; ++j)
                    #pragma unroll
                    for (int r = 0; r < 4; ++r)
                        Ebf[(i * 16 + q * 4 + r) * 132 + ncol + j * 16 + l15] = acc[i][j][r];
        }
        __syncthreads();
        {
            const int row = tid >> 2, seg = tid & 3;    // 64 rows x 4 segs of 32
            const int m = ch * 64 + row;                // jc
            // H chunk-packed: half-index = c*1536 + d0*2 + dl
            _Float16* hp = Hh + (size_t)(ib * 128 + m) * 1536 + d0 * 2 + seg * 32;
            #pragma unroll
            for (int u = 0; u < 4; ++u) {
                const float* sp = Ebf + row * 132 + seg * 32 + u * 8;
                half8 hv;
                #pragma unroll
                for (int e = 0; e < 8; ++e) hv[e] = (_Float16)sp[e];
                *(half8*)(hp + u * 8) = hv;
            }
        }
        __syncthreads();
    }
}

// ---- conv pass B (MFMA) + fused S-conv + epilogue:
//      out[(ic,jc),d] = w*(1-a*S[ic,jc]) + a * sum_i E[ic,i] H[(i,jc),d]
__global__ __launch_bounds__(256) void convB_kernel(
    const _Float16* Hh, const float* __restrict__ w, const float* __restrict__ cnt,
    const int* __restrict__ itp, float* __restrict__ out) {
    __shared__ _Float16 Es[128 * EP];
    __shared__ _Float16 Bs[128 * BP];
    __shared__ float cntHs[128];
    __shared__ float Ss[128];
    const int d0 = blockIdx.x * 128;    // 0..5
    const int jc = blockIdx.y;          // 0..127
    const int tid = threadIdx.x;
    const int wv = tid >> 6, lane = tid & 63;
    const int l15 = lane & 15, q = lane >> 4;
    const int mrow = (wv >> 1) * 64, ncol = (wv & 1) * 64;
    const float decay = 1.f - (float)(*itp) / NITER_F;
    const float alpha = ALPHA0 * decay;
    const float sig = SIGMA0 * decay;
    const float inv = -1.f / (sig * sig);

    // count-conv for this jc column (S[ic] for all ic), fp32
    if (tid < 128) {
        float s = 0.f;
        for (int j = 0; j < 128; ++j) {
            const float dd = (float)(jc - j);
            s += __expf(dd * dd * inv) * cnt[tid * 128 + j];
        }
        cntHs[tid] = s;
    }
    {   // compute E tile in LDS
        const int row = tid >> 1, hh = tid & 1;
        _Float16* dst = Es + row * EP + hh * 64;
        #pragma unroll
        for (int u = 0; u < 64; ++u) {
            const float dd = (float)(row - hh * 64 - u);
            dst[u] = (_Float16)__expf(dd * dd * inv);
        }
    }
    __syncthreads();
    if (tid < 128) {
        float s = 0.f;
        for (int i = 0; i < 128; ++i) {
            const float dd = (float)(tid - i);
            s += __expf(dd * dd * inv) * cntHs[i];
        }
        Ss[tid] = s;
    }

    floatx4 acc[4][4];
    #pragma unroll
    for (int i = 0; i < 4; ++i)
        #pragma unroll
        for (int j = 0; j < 4; ++j) acc[i][j] = (floatx4){0.f, 0.f, 0.f, 0.f};

    const int dpo = (tid & 15) * 8;
    const int rsel = tid >> 4;
    for (int k0 = 0; k0 < 128; k0 += 32) {
        __syncthreads();
        #pragma unroll
        for (int s = 0; s < 2; ++s) {   // coalesced: 16 lanes read one row's 256B chunk
            const int i = k0 + s * 16 + rsel;
            const half8 v = *(const half8*)(Hh + (size_t)(i * 128 + jc) * 1536 + d0 * 2 + dpo);
            #pragma unroll
            for (int u = 0; u < 8; ++u)
                Bs[(dpo + u) * BP + (s * 16 + rsel)] = v[u];
        }
        __syncthreads();
        half8 af[4], bf[4];
        #pragma unroll
        for (int i = 0; i < 4; ++i)
            af[i] = *(const half8*)(Es + (mrow + i * 16 + l15) * EP + k0 + q * 8);
        #pragma unroll
        for (int j = 0; j < 4; ++j)
            bf[j] = *(const half8*)(Bs + (ncol + j * 16 + l15) * BP + q * 8);
        #pragma unroll
        for (int i = 0; i < 4; ++i)
            #pragma unroll
            for (int j = 0; j < 4; ++j)
                acc[i][j] = __builtin_amdgcn_mfma_f32_16x16x32_f16(af[i], bf[j], acc[i][j], 0, 0, 0);
    }
    __syncthreads();
    // fused epilogue: fp32 bounce in 2 chunks of 64 rows (m = ic)
    float* Ebf = (float*)Es;            // [64][132] floats
    #pragma unroll
    for (int ch = 0; ch < 2; ++ch) {
        if ((wv >> 1) == ch) {
            #pragma unroll
            for (int i = 0; i < 4; ++i)
                #pragma unroll
                for (int j = 0; j < 4; ++j)
                    #pragma unroll
                    for (int r = 0; r < 4; ++r)
                        Ebf[(i * 16 + q * 4 + r) * 132 + ncol + j * 16 + l15] = acc[i][j][r];
        }
        __syncthreads();
        {
            const int row = tid >> 2, seg = tid & 3;    // 64 rows x 4 segs of 32 floats
            const int m = ch * 64 + row;                // ic
            const int c = m * 128 + jc;
            const float scl = 1.f - alpha * Ss[m];
            const size_t g = (size_t)c * DIM + d0 + seg * 32;
            #pragma unroll
            for (int u = 0; u < 8; ++u) {
                float4 wv4 = *(const float4*)(w + g + u * 4);
                float4 t4  = *(const float4*)(Ebf + row * 132 + seg * 32 + u * 4);
                float4 o;
                o.x = wv4.x * scl + alpha * t4.x;
                o.y = wv4.y * scl + alpha * t4.y;
                o.z = wv4.z * scl + alpha * t4.z;
                o.w = wv4.w * scl + alpha * t4.w;
                *(float4*)(out + g + u * 4) = o;
            }
        }
        __syncthreads();
    }
}

extern "C" void kernel_launch(void* const* d_in, const int* in_sizes, int n_in,
                              void* d_out, int out_size, void* d_ws, size_t ws_size,
                              hipStream_t stream) {
    const float* x  = (const float*)d_in[0];   // [4096, 768]
    const float* w  = (const float*)d_in[1];   // [16384, 768]
    const int* itp  = (const int*)d_in[2];     // scalar it
    float* out = (float*)d_out;                // [16384, 768]
    char* ws = (char*)d_ws;

    _Float16* xh = (_Float16*)(ws + XH_OFF);
    _Float16* wh = (_Float16*)(ws + WH_OFF);
    float*    G  = (float*)(ws + G_OFF);       // aliases xh/wh, used post-bmu
    _Float16* Hh = (_Float16*)(ws + G_OFF);    // H fp16 chunk-packed inside G rows
    unsigned long long* best = (unsigned long long*)(ws + BEST_OFF);
    float* cnt  = (float*)(ws + CNT_OFF);
    float* wn2  = (float*)(ws + WN2_OFF);

    hipMemsetAsync(ws + BEST_OFF, 0, BEST_BYTES + CNT_BYTES, stream);

    cvt_kernel<<<(BS * DIM / 4 + 255) / 256, 256, 0, stream>>>(x, xh, BS * DIM / 4);
    cvtw_wn2_kernel<<<COMPS, 192, 0, stream>>>(w, wh, wn2);

    // 1024 blocks = 16 b-tiles x 64 c-tiles (XCD-remapped inside the kernel)
    bmu_kernel<<<dim3(1024), 512, 0, stream>>>(xh, wh, wn2, best);

    // xh/wh dead -> zero full G (stream-ordered after bmu)
    hipMemsetAsync(ws + G_OFF, 0, G_BYTES, stream);
    scatter_kernel<<<BS, 256, 0, stream>>>(best, x, G, cnt);

    // pass A: H fp16 (chunk-packed into G storage)
    convA_kernel<<<dim3(6, 128), 256, 0, stream>>>(G, Hh, itp);
    // pass B + count-conv + epilogue -> d_out
    convB_kernel<<<dim3(6, 128), 256, 0, stream>>>(Hh, w, cnt, itp, out);
}

// Round 6
// 386.260 us; speedup vs baseline: 5.2950x; 5.2950x over previous
//
#include <hip/hip_runtime.h>
#include <cstdint>
#include <cstddef>

// ---------------- problem constants ----------------
#define BS    4096
#define DIM   768
#define GM    128
#define GN    128
#define COMPS (GM * GN)          // 16384
#define NITER_F 1000.0f
#define ALPHA0  0.3f
#define SIGMA0  64.0f            // max(M,N)/2

typedef _Float16 half8  __attribute__((ext_vector_type(8)));
typedef _Float16 half4v __attribute__((ext_vector_type(4)));
typedef float    floatx4 __attribute__((ext_vector_type(4)));
typedef float    floatx16 __attribute__((ext_vector_type(16)));

// ---------------- workspace layout (bytes) ----------------
// Phase 1 (pre-bmu): xh fp16 @0 (6.3MB), wh fp16 @8MB (25.2MB).
// Phase 2 (post-bmu): G fp32 full-width @0 (50.33MB) — aliases xh/wh (dead).
// H fp16 lives packed INSIDE G's rows (see convA). Tails: best, cnt, wn2.
#define XH_OFF    0UL
#define WH_OFF    (8UL * 1024UL * 1024UL)
#define G_OFF     0UL
#define G_BYTES   ((size_t)COMPS * DIM * 4UL)     // 50,331,648
#define BEST_OFF  G_BYTES
#define BEST_BYTES ((size_t)BS * 8UL)             // 32 KB
#define CNT_OFF   (BEST_OFF + BEST_BYTES)
#define CNT_BYTES ((size_t)COMPS * 4UL)           // 64 KB
#define WN2_OFF   (CNT_OFF + CNT_BYTES)

#define GPTR(p) ((const __attribute__((address_space(1))) void*)(p))
#define LPTR(p) ((__attribute__((address_space(3))) void*)(p))

// pack (score, index) so that u64 max == (max score, min index on ties)
__device__ __forceinline__ unsigned long long packScore(float s, int c) {
    unsigned u = __float_as_uint(s);
    u = (u & 0x80000000u) ? ~u : (u | 0x80000000u);   // order-preserving map
    return ((unsigned long long)u << 32) | (unsigned)(~(unsigned)c);
}

__device__ __forceinline__ unsigned long long shfl_xor_u64(unsigned long long v, int m) {
    unsigned lo = (unsigned)v, hi = (unsigned)(v >> 32);
    lo = (unsigned)__shfl_xor((int)lo, m, 64);
    hi = (unsigned)__shfl_xor((int)hi, m, 64);
    return ((unsigned long long)hi << 32) | lo;
}

// ---------------- fp32 -> fp16 convert (x) ----------------
__global__ void cvt_kernel(const float* __restrict__ src, _Float16* __restrict__ dst, int n4) {
    int i = blockIdx.x * 256 + threadIdx.x;
    if (i >= n4) return;
    float4 v = ((const float4*)src)[i];
    half4v h;
    h[0] = (_Float16)v.x; h[1] = (_Float16)v.y;
    h[2] = (_Float16)v.z; h[3] = (_Float16)v.w;
    ((half4v*)dst)[i] = h;
}

// ---------------- w: fp32->fp16 convert fused with 0.5*||w_c||^2 ----------------
__global__ __launch_bounds__(192) void cvtw_wn2_kernel(
    const float* __restrict__ w, _Float16* __restrict__ wh, float* __restrict__ wn2) {
    const int c = blockIdx.x;
    const int t = threadIdx.x;                   // 0..191 (one float4 each)
    const size_t i4 = (size_t)c * 192 + t;
    float4 v = ((const float4*)w)[i4];
    half4v h;
    h[0] = (_Float16)v.x; h[1] = (_Float16)v.y;
    h[2] = (_Float16)v.z; h[3] = (_Float16)v.w;
    ((half4v*)wh)[i4] = h;
    float s = v.x * v.x + v.y * v.y + v.z * v.z + v.w * v.w;
    #pragma unroll
    for (int off = 32; off; off >>= 1) s += __shfl_down(s, off, 64);
    __shared__ float p[3];
    if ((t & 63) == 0) p[t >> 6] = s;
    __syncthreads();
    if (t == 0) wn2[c] = 0.5f * (p[0] + p[1] + p[2]);
}

// ---------------- MFMA BMU v5: v2 skeleton + v3 locality remap + 32x32x16 MFMA ----
// best_b = argmax_c (x_b.w_c - 0.5||w_c||^2).
// 256x256 tile, BK=32, 8 waves (2M x 4N), per-wave 128x64 output as 4x2 tiles
// of 32x32 (acc floatx16[4][2] = 128 regs). __launch_bounds__(512, 2): 256-VGPR
// budget — v4's (512,4) capped at 128 and spilled the accumulator to scratch
// (VGPR_Count 64, 9.6GB scratch traffic, 13x regression).
// Loop = v2's proven skeleton: 4-deep ring, ONE barrier per K-tile, counted
// s_waitcnt vmcnt(8) (never 0 midloop), staging interleaved between MFMA
// clusters, NO lgkmcnt pinning (v3's barrier-pair phase split regressed).
// Ring invariants as v2: stage(t+3) issued after the barrier that proves all
// reads of tile t-1 (same buffer) are consumed; vmcnt(8) at top retires tile
// t's 4 loads (12 in flight steady-state); tail drains 8->4->0.
// LDS layout as v2: line = row>>1 (128B line = row pair), phys slot =
// ((row&1)<<2 | kchunk) ^ (line&7), global source pre-swizzled so the linear
// global_load_lds dest matches. 32x32 fragment: kchunk = h*2 + (lane>>5);
// per-16-lane phase each 16B slot is hit exactly 2x -> free 2-way.
#define BMU_NT 24   // 768 / 32

__global__ __launch_bounds__(512, 2) void bmu_kernel(
    const _Float16* __restrict__ xh, const _Float16* __restrict__ wh,
    const float* __restrict__ wn2, unsigned long long* __restrict__ best) {
    __shared__ _Float16 AB[4][2][8192];       // [buf][A,B][128 lines x 64 halves]
    __shared__ unsigned long long red[256];

    const int tid  = threadIdx.x;
    const int wv   = tid >> 6;
    const int lane = tid & 63;
    const int l31  = lane & 31;
    const int hsel = lane >> 5;      // k-octet selector within K=16
    const int wr   = wv >> 2;        // 0..1 (M half)
    const int wc   = wv & 3;         // 0..3 (N quarter)

    // XCD-aware remap (v3, measured FETCH 110->71MB): each XCD owns 8 w-tiles;
    // concurrent window = 4 w-tiles x 8 x-tiles = 4.7MB vs 4MB L2.
    const int bid = blockIdx.x;      // 0..1023
    const int xcd = bid & 7;
    const int rem = bid >> 3;        // 0..127
    const int cbl = rem & 3;         // w tile (inner, 4 concurrent)
    const int bb  = (rem >> 2) & 15; // x tile (middle)
    const int cbg = rem >> 6;        // 0..1 (outer w group)
    const int cb  = xcd * 8 + cbg * 4 + cbl;
    const int b0 = bb * 256;
    const int c0 = cb * 256;

    if (tid < 256) red[tid] = 0ULL;

    // staging source decomposition (pre-swizzled global addresses) — as v2.
    const int Ls = tid >> 3;         // line within round
    const int ss = tid & 7;          // phys slot == linear dest slot
    const int sl = ss ^ (Ls & 7);    // logical slot
    const int prow = 2 * Ls + (sl >> 2);     // row within 128-row half
    const int kc8  = (sl & 3) * 8;           // k-chunk offset (halves)
    const _Float16* gA0 = xh + (size_t)(b0 + prow) * DIM + kc8;
    const _Float16* gA1 = gA0 + (size_t)128 * DIM;
    const _Float16* gB0 = wh + (size_t)(c0 + prow) * DIM + kc8;
    const _Float16* gB1 = gB0 + (size_t)128 * DIM;
    const int ldsoff = wv * 512;     // halves: wave-uniform base

    // fragment LDS offsets (halves): A 4 mtiles x 2 k-halves, B 2 ntiles x 2
    int aoff[4][2], boff[2][2];
    #pragma unroll
    for (int i = 0; i < 4; ++i)
        #pragma unroll
        for (int h = 0; h < 2; ++h) {
            const int row = wr * 128 + i * 32 + l31;
            const int line = row >> 1;
            const int ck = h * 2 + hsel;
            const int ps = (((row & 1) << 2) | ck) ^ (line & 7);
            aoff[i][h] = line * 64 + ps * 8;
        }
    #pragma unroll
    for (int j = 0; j < 2; ++j)
        #pragma unroll
        for (int h = 0; h < 2; ++h) {
            const int row = wc * 64 + j * 32 + l31;
            const int line = row >> 1;
            const int ck = h * 2 + hsel;
            const int ps = (((row & 1) << 2) | ck) ^ (line & 7);
            boff[j][h] = line * 64 + ps * 8;
        }

    floatx16 acc[4][2];
    #pragma unroll
    for (int i = 0; i < 4; ++i)
        #pragma unroll
        for (int j = 0; j < 2; ++j)
            #pragma unroll
            for (int r = 0; r < 16; ++r) acc[i][j][r] = 0.f;

    // prologue: stage tiles 0..2 (4 global_load_lds each per thread)
    #pragma unroll
    for (int t = 0; t < 3; ++t) {
        _Float16* A = &AB[t][0][0];
        _Float16* B = &AB[t][1][0];
        __builtin_amdgcn_global_load_lds(GPTR(gA0 + t * 32), LPTR(A + ldsoff),        16, 0, 0);
        __builtin_amdgcn_global_load_lds(GPTR(gA1 + t * 32), LPTR(A + 4096 + ldsoff), 16, 0, 0);
        __builtin_amdgcn_global_load_lds(GPTR(gB0 + t * 32), LPTR(B + ldsoff),        16, 0, 0);
        __builtin_amdgcn_global_load_lds(GPTR(gB1 + t * 32), LPTR(B + 4096 + ldsoff), 16, 0, 0);
    }

    for (int t = 0; t < BMU_NT; ++t) {
        // counted drain: own loads of tile t retired; t+1.. stay in flight
        if (t < BMU_NT - 2)       asm volatile("s_waitcnt vmcnt(8)" ::: "memory");
        else if (t == BMU_NT - 2) asm volatile("s_waitcnt vmcnt(4)" ::: "memory");
        else                      asm volatile("s_waitcnt vmcnt(0)" ::: "memory");
        __builtin_amdgcn_s_barrier();
        asm volatile("" ::: "memory");   // no LDS-read hoisting above the barrier

        const _Float16* A = &AB[t & 3][0][0];
        const _Float16* B = &AB[t & 3][1][0];
        const bool more = (t + 3) < BMU_NT;
        _Float16* An = &AB[(t + 3) & 3][0][0];
        _Float16* Bn = &AB[(t + 3) & 3][1][0];
        const int t3 = (t + 3) * 32;

        half8 af[4][2], bf[2][2];
        // phase 0: i0-1 x j0
        af[0][0] = *(const half8*)(A + aoff[0][0]);
        af[0][1] = *(const half8*)(A + aoff[0][1]);
        af[1][0] = *(const half8*)(A + aoff[1][0]);
        af[1][1] = *(const half8*)(A + aoff[1][1]);
        bf[0][0] = *(const half8*)(B + boff[0][0]);
        bf[0][1] = *(const half8*)(B + boff[0][1]);
        if (more) __builtin_amdgcn_global_load_lds(GPTR(gA0 + t3), LPTR(An + ldsoff), 16, 0, 0);
        __builtin_amdgcn_s_setprio(1);
        acc[0][0] = __builtin_amdgcn_mfma_f32_32x32x16_f16(af[0][0], bf[0][0], acc[0][0], 0, 0, 0);
        acc[1][0] = __builtin_amdgcn_mfma_f32_32x32x16_f16(af[1][0], bf[0][0], acc[1][0], 0, 0, 0);
        acc[0][0] = __builtin_amdgcn_mfma_f32_32x32x16_f16(af[0][1], bf[0][1], acc[0][0], 0, 0, 0);
        acc[1][0] = __builtin_amdgcn_mfma_f32_32x32x16_f16(af[1][1], bf[0][1], acc[1][0], 0, 0, 0);
        __builtin_amdgcn_s_setprio(0);
        // phase 1: i2-3 x j0
        af[2][0] = *(const half8*)(A + aoff[2][0]);
        af[2][1] = *(const half8*)(A + aoff[2][1]);
        af[3][0] = *(const half8*)(A + aoff[3][0]);
        af[3][1] = *(const half8*)(A + aoff[3][1]);
        if (more) __builtin_amdgcn_global_load_lds(GPTR(gA1 + t3), LPTR(An + 4096 + ldsoff), 16, 0, 0);
        __builtin_amdgcn_s_setprio(1);
        acc[2][0] = __builtin_amdgcn_mfma_f32_32x32x16_f16(af[2][0], bf[0][0], acc[2][0], 0, 0, 0);
        acc[3][0] = __builtin_amdgcn_mfma_f32_32x32x16_f16(af[3][0], bf[0][0], acc[3][0], 0, 0, 0);
        acc[2][0] = __builtin_amdgcn_mfma_f32_32x32x16_f16(af[2][1], bf[0][1], acc[2][0], 0, 0, 0);
        acc[3][0] = __builtin_amdgcn_mfma_f32_32x32x16_f16(af[3][1], bf[0][1], acc[3][0], 0, 0, 0);
        __builtin_amdgcn_s_setprio(0);
        // phase 2: i0-1 x j1
        bf[1][0] = *(const half8*)(B + boff[1][0]);
        bf[1][1] = *(const half8*)(B + boff[1][1]);
        if (more) __builtin_amdgcn_global_load_lds(GPTR(gB0 + t3), LPTR(Bn + ldsoff), 16, 0, 0);
        __builtin_amdgcn_s_setprio(1);
        acc[0][1] = __builtin_amdgcn_mfma_f32_32x32x16_f16(af[0][0], bf[1][0], acc[0][1], 0, 0, 0);
        acc[1][1] = __builtin_amdgcn_mfma_f32_32x32x16_f16(af[1][0], bf[1][0], acc[1][1], 0, 0, 0);
        acc[0][1] = __builtin_amdgcn_mfma_f32_32x32x16_f16(af[0][1], bf[1][1], acc[0][1], 0, 0, 0);
        acc[1][1] = __builtin_amdgcn_mfma_f32_32x32x16_f16(af[1][1], bf[1][1], acc[1][1], 0, 0, 0);
        __builtin_amdgcn_s_setprio(0);
        // phase 3: i2-3 x j1
        if (more) __builtin_amdgcn_global_load_lds(GPTR(gB1 + t3), LPTR(Bn + 4096 + ldsoff), 16, 0, 0);
        __builtin_amdgcn_s_setprio(1);
        acc[2][1] = __builtin_amdgcn_mfma_f32_32x32x16_f16(af[2][0], bf[1][0], acc[2][1], 0, 0, 0);
        acc[3][1] = __builtin_amdgcn_mfma_f32_32x32x16_f16(af[3][0], bf[1][0], acc[3][1], 0, 0, 0);
        acc[2][1] = __builtin_amdgcn_mfma_f32_32x32x16_f16(af[2][1], bf[1][1], acc[2][1], 0, 0, 0);
        acc[3][1] = __builtin_amdgcn_mfma_f32_32x32x16_f16(af[3][1], bf[1][1], acc[3][1], 0, 0, 0);
        __builtin_amdgcn_s_setprio(0);
    }

    // ---------------- argmax epilogue (32x32 C/D map) ----------------
    // col = lane&31 (c index), row = (r&3) + 8*(r>>2) + 4*(lane>>5) (b index)
    float wnj[2];
    #pragma unroll
    for (int j = 0; j < 2; ++j) wnj[j] = wn2[c0 + wc * 64 + j * 32 + l31];

    #pragma unroll
    for (int i = 0; i < 4; ++i) {
        #pragma unroll
        for (int r = 0; r < 16; ++r) {
            unsigned long long m = 0ULL;
            #pragma unroll
            for (int j = 0; j < 2; ++j) {
                const float s = acc[i][j][r] - wnj[j];
                const unsigned long long p = packScore(s, c0 + wc * 64 + j * 32 + l31);
                if (p > m) m = p;
            }
            #pragma unroll
            for (int msk = 1; msk <= 16; msk <<= 1) {
                const unsigned long long o = shfl_xor_u64(m, msk);
                if (o > m) m = o;
            }
            if (l31 == 0)
                atomicMax(&red[wr * 128 + i * 32 + (r & 3) + 8 * (r >> 2) + 4 * hsel], m);
        }
    }
    __syncthreads();
    if (tid < 256) atomicMax(&best[b0 + tid], red[tid]);
}

// ---------------- scatter x rows into full-width G + histogram ----------------
__global__ void scatter_kernel(const unsigned long long* __restrict__ best,
                               const float* __restrict__ x,
                               float* __restrict__ G, float* __restrict__ cnt) {
    const int b = blockIdx.x;
    const int c = (int)(~(unsigned)(best[b] & 0xFFFFFFFFULL));
    float* gr = G + (size_t)c * DIM;
    const float* xr = x + (size_t)b * DIM;
    #pragma unroll
    for (int u = 0; u < 3; ++u) {
        const int d = threadIdx.x + u * 256;
        atomicAdd(&gr[d], xr[d]);
    }
    if (threadIdx.x == 0) atomicAdd(&cnt[c], 1.0f);
}

#define EP 136   // Es pitch (halves)
#define BP 40    // Bs pitch (halves)

// ---- conv pass A (MFMA): H[(i,jc), d] = sum_j E[jc,j] * G[(i,j), d]; H fp16 packed into G rows ----
__global__ __launch_bounds__(256) void convA_kernel(
    const float* G, _Float16* Hh, const int* __restrict__ itp) {
    __shared__ _Float16 Es[128 * EP];   // E fp16, later reused as fp32 bounce
    __shared__ _Float16 Bs[128 * BP];
    const int d0 = blockIdx.x * 128;    // 0..5
    const int ib = blockIdx.y;          // 0..127
    const int tid = threadIdx.x;
    const int wv = tid >> 6, lane = tid & 63;
    const int l15 = lane & 15, q = lane >> 4;
    const int mrow = (wv >> 1) * 64, ncol = (wv & 1) * 64;

    {   // compute E tile in LDS on the fly
        const float decay = 1.f - (float)(*itp) / NITER_F;
        const float sig = SIGMA0 * decay;
        const float inv = -1.f / (sig * sig);
        const int row = tid >> 1, hh = tid & 1;
        _Float16* dst = Es + row * EP + hh * 64;
        #pragma unroll
        for (int u = 0; u < 64; ++u) {
            const float dd = (float)(row - hh * 64 - u);
            dst[u] = (_Float16)__expf(dd * dd * inv);
        }
    }

    floatx4 acc[4][4];
    #pragma unroll
    for (int i = 0; i < 4; ++i)
        #pragma unroll
        for (int j = 0; j < 4; ++j) acc[i][j] = (floatx4){0.f, 0.f, 0.f, 0.f};

    const int dpo = (tid & 15) * 8;     // d-octet within 128
    const int rsel = tid >> 4;          // 0..15 row selector
    for (int k0 = 0; k0 < 128; k0 += 32) {
        __syncthreads();
        #pragma unroll
        for (int s = 0; s < 2; ++s) {   // coalesced: 16 lanes read one row's 512B
            const int j = k0 + s * 16 + rsel;
            const float* r = G + (size_t)(ib * 128 + j) * DIM + d0 + dpo;
            float4 a0 = *(const float4*)r, a1 = *(const float4*)(r + 4);
            float va[8] = {a0.x, a0.y, a0.z, a0.w, a1.x, a1.y, a1.z, a1.w};
            #pragma unroll
            for (int u = 0; u < 8; ++u)
                Bs[(dpo + u) * BP + (s * 16 + rsel)] = (_Float16)va[u];
        }
        __syncthreads();
        half8 af[4], bf[4];
        #pragma unroll
        for (int i = 0; i < 4; ++i)
            af[i] = *(const half8*)(Es + (mrow + i * 16 + l15) * EP + k0 + q * 8);
        #pragma unroll
        for (int j = 0; j < 4; ++j)
            bf[j] = *(const half8*)(Bs + (ncol + j * 16 + l15) * BP + q * 8);
        #pragma unroll
        for (int i = 0; i < 4; ++i)
            #pragma unroll
            for (int j = 0; j < 4; ++j)
                acc[i][j] = __builtin_amdgcn_mfma_f32_16x16x32_f16(af[i], bf[j], acc[i][j], 0, 0, 0);
    }
    __syncthreads();
    // fp32 bounce epilogue in 2 chunks of 64 rows (m = jc), write H fp16 chunk-packed
    float* Ebf = (float*)Es;            // [64][132] floats = 33792 B <= 34816
    #pragma unroll
    for (int ch = 0; ch < 2; ++ch) {
        if ((wv >> 1) == ch) {
            #pragma unroll
            for (int i = 0; i < 4; ++i)
                #pragma unroll
                for (int j = 0; j < 4; ++j)
                    #pragma unroll
                    for (int r = 0; r < 4; ++r)
                        Ebf[(i * 16 + q * 4 + r) * 132 + ncol + j * 16 + l15] = acc[i][j][r];
        }
        __syncthreads();
        {
            const int row = tid >> 2, seg = tid & 3;    // 64 rows x 4 segs of 32
            const int m = ch * 64 + row;                // jc
            // H chunk-packed: half-index = c*1536 + d0*2 + dl
            _Float16* hp = Hh + (size_t)(ib * 128 + m) * 1536 + d0 * 2 + seg * 32;
            #pragma unroll
            for (int u = 0; u < 4; ++u) {
                const float* sp = Ebf + row * 132 + seg * 32 + u * 8;
                half8 hv;
                #pragma unroll
                for (int e = 0; e < 8; ++e) hv[e] = (_Float16)sp[e];
                *(half8*)(hp + u * 8) = hv;
            }
        }
        __syncthreads();
    }
}

// ---- conv pass B (MFMA) + fused S-conv + epilogue:
//      out[(ic,jc),d] = w*(1-a*S[ic,jc]) + a * sum_i E[ic,i] H[(i,jc),d]
__global__ __launch_bounds__(256) void convB_kernel(
    const _Float16* Hh, const float* __restrict__ w, const float* __restrict__ cnt,
    const int* __restrict__ itp, float* __restrict__ out) {
    __shared__ _Float16 Es[128 * EP];
    __shared__ _Float16 Bs[128 * BP];
    __shared__ float cntHs[128];
    __shared__ float Ss[128];
    const int d0 = blockIdx.x * 128;    // 0..5
    const int jc = blockIdx.y;          // 0..127
    const int tid = threadIdx.x;
    const int wv = tid >> 6, lane = tid & 63;
    const int l15 = lane & 15, q = lane >> 4;
    const int mrow = (wv >> 1) * 64, ncol = (wv & 1) * 64;
    const float decay = 1.f - (float)(*itp) / NITER_F;
    const float alpha = ALPHA0 * decay;
    const float sig = SIGMA0 * decay;
    const float inv = -1.f / (sig * sig);

    // count-conv for this jc column (S[ic] for all ic), fp32
    if (tid < 128) {
        float s = 0.f;
        for (int j = 0; j < 128; ++j) {
            const float dd = (float)(jc - j);
            s += __expf(dd * dd * inv) * cnt[tid * 128 + j];
        }
        cntHs[tid] = s;
    }
    {   // compute E tile in LDS
        const int row = tid >> 1, hh = tid & 1;
        _Float16* dst = Es + row * EP + hh * 64;
        #pragma unroll
        for (int u = 0; u < 64; ++u) {
            const float dd = (float)(row - hh * 64 - u);
            dst[u] = (_Float16)__expf(dd * dd * inv);
        }
    }
    __syncthreads();
    if (tid < 128) {
        float s = 0.f;
        for (int i = 0; i < 128; ++i) {
            const float dd = (float)(tid - i);
            s += __expf(dd * dd * inv) * cntHs[i];
        }
        Ss[tid] = s;
    }

    floatx4 acc[4][4];
    #pragma unroll
    for (int i = 0; i < 4; ++i)
        #pragma unroll
        for (int j = 0; j < 4; ++j) acc[i][j] = (floatx4){0.f, 0.f, 0.f, 0.f};

    const int dpo = (tid & 15) * 8;
    const int rsel = tid >> 4;
    for (int k0 = 0; k0 < 128; k0 += 32) {
        __syncthreads();
        #pragma unroll
        for (int s = 0; s < 2; ++s) {   // coalesced: 16 lanes read one row's 256B chunk
            const int i = k0 + s * 16 + rsel;
            const half8 v = *(const half8*)(Hh + (size_t)(i * 128 + jc) * 1536 + d0 * 2 + dpo);
            #pragma unroll
            for (int u = 0; u < 8; ++u)
                Bs[(dpo + u) * BP + (s * 16 + rsel)] = v[u];
        }
        __syncthreads();
        half8 af[4], bf[4];
        #pragma unroll
        for (int i = 0; i < 4; ++i)
            af[i] = *(const half8*)(Es + (mrow + i * 16 + l15) * EP + k0 + q * 8);
        #pragma unroll
        for (int j = 0; j < 4; ++j)
            bf[j] = *(const half8*)(Bs + (ncol + j * 16 + l15) * BP + q * 8);
        #pragma unroll
        for (int i = 0; i < 4; ++i)
            #pragma unroll
            for (int j = 0; j < 4; ++j)
                acc[i][j] = __builtin_amdgcn_mfma_f32_16x16x32_f16(af[i], bf[j], acc[i][j], 0, 0, 0);
    }
    __syncthreads();
    // fused epilogue: fp32 bounce in 2 chunks of 64 rows (m = ic)
    float* Ebf = (float*)Es;            // [64][132] floats
    #pragma unroll
    for (int ch = 0; ch < 2; ++ch) {
        if ((wv >> 1) == ch) {
            #pragma unroll
            for (int i = 0; i < 4; ++i)
                #pragma unroll
                for (int j = 0; j < 4; ++j)
                    #pragma unroll
                    for (int r = 0; r < 4; ++r)
                        Ebf[(i * 16 + q * 4 + r) * 132 + ncol + j * 16 + l15] = acc[i][j][r];
        }
        __syncthreads();
        {
            const int row = tid >> 2, seg = tid & 3;    // 64 rows x 4 segs of 32 floats
            const int m = ch * 64 + row;                // ic
            const int c = m * 128 + jc;
            const float scl = 1.f - alpha * Ss[m];
            const size_t g = (size_t)c * DIM + d0 + seg * 32;
            #pragma unroll
            for (int u = 0; u < 8; ++u) {
                float4 wv4 = *(const float4*)(w + g + u * 4);
                float4 t4  = *(const float4*)(Ebf + row * 132 + seg * 32 + u * 4);
                float4 o;
                o.x = wv4.x * scl + alpha * t4.x;
                o.y = wv4.y * scl + alpha * t4.y;
                o.z = wv4.z * scl + alpha * t4.z;
                o.w = wv4.w * scl + alpha * t4.w;
                *(float4*)(out + g + u * 4) = o;
            }
        }
        __syncthreads();
    }
}

extern "C" void kernel_launch(void* const* d_in, const int* in_sizes, int n_in,
                              void* d_out, int out_size, void* d_ws, size_t ws_size,
                              hipStream_t stream) {
    const float* x  = (const float*)d_in[0];   // [4096, 768]
    const float* w  = (const float*)d_in[1];   // [16384, 768]
    const int* itp  = (const int*)d_in[2];     // scalar it
    float* out = (float*)d_out;                // [16384, 768]
    char* ws = (char*)d_ws;

    _Float16* xh = (_Float16*)(ws + XH_OFF);
    _Float16* wh = (_Float16*)(ws + WH_OFF);
    float*    G  = (float*)(ws + G_OFF);       // aliases xh/wh, used post-bmu
    _Float16* Hh = (_Float16*)(ws + G_OFF);    // H fp16 chunk-packed inside G rows
    unsigned long long* best = (unsigned long long*)(ws + BEST_OFF);
    float* cnt  = (float*)(ws + CNT_OFF);
    float* wn2  = (float*)(ws + WN2_OFF);

    hipMemsetAsync(ws + BEST_OFF, 0, BEST_BYTES + CNT_BYTES, stream);

    cvt_kernel<<<(BS * DIM / 4 + 255) / 256, 256, 0, stream>>>(x, xh, BS * DIM / 4);
    cvtw_wn2_kernel<<<COMPS, 192, 0, stream>>>(w, wh, wn2);

    // 1024 blocks = 16 b-tiles x 64 c-tiles (XCD-remapped inside the kernel)
    bmu_kernel<<<dim3(1024), 512, 0, stream>>>(xh, wh, wn2, best);

    // xh/wh dead -> zero full G (stream-ordered after bmu)
    hipMemsetAsync(ws + G_OFF, 0, G_BYTES, stream);
    scatter_kernel<<<BS, 256, 0, stream>>>(best, x, G, cnt);

    // pass A: H fp16 (chunk-packed into G storage)
    convA_kernel<<<dim3(6, 128), 256, 0, stream>>>(G, Hh, itp);
    // pass B + count-conv + epilogue -> d_out
    convB_kernel<<<dim3(6, 128), 256, 0, stream>>>(Hh, w, cnt, itp, out);
}

// Round 8
// 336.513 us; speedup vs baseline: 6.0777x; 1.1478x over previous
//
#include <hip/hip_runtime.h>
#include <cstdint>
#include <cstddef>

// ---------------- problem constants ----------------
#define BS    4096
#define DIM   768
#define GM    128
#define GN    128
#define COMPS (GM * GN)          // 16384
#define NITER_F 1000.0f
#define ALPHA0  0.3f
#define SIGMA0  64.0f            // max(M,N)/2

typedef _Float16 half8  __attribute__((ext_vector_type(8)));
typedef _Float16 half4v __attribute__((ext_vector_type(4)));
typedef float    floatx4 __attribute__((ext_vector_type(4)));

// ---------------- workspace layout (bytes) ----------------
// Phase 1 (pre-bmu): xh fp16 @0 (6.3MB), wh fp16 @8MB (25.2MB).
// Phase 2 (post-bmu): G fp32 full-width @0 (50.33MB) — aliases xh/wh (dead).
// H fp16 lives packed INSIDE G's rows (see convA). Tails: best, cnt, wn2.
#define XH_OFF    0UL
#define WH_OFF    (8UL * 1024UL * 1024UL)
#define G_OFF     0UL
#define G_BYTES   ((size_t)COMPS * DIM * 4UL)     // 50,331,648
#define BEST_OFF  G_BYTES
#define BEST_BYTES ((size_t)BS * 8UL)             // 32 KB
#define CNT_OFF   (BEST_OFF + BEST_BYTES)
#define CNT_BYTES ((size_t)COMPS * 4UL)           // 64 KB
#define WN2_OFF   (CNT_OFF + CNT_BYTES)

#define GPTR(p) ((const __attribute__((address_space(1))) void*)(p))
#define LPTR(p) ((__attribute__((address_space(3))) void*)(p))

// pack (score, index) so that u64 max == (max score, min index on ties)
__device__ __forceinline__ unsigned long long packScore(float s, int c) {
    unsigned u = __float_as_uint(s);
    u = (u & 0x80000000u) ? ~u : (u | 0x80000000u);   // order-preserving map
    return ((unsigned long long)u << 32) | (unsigned)(~(unsigned)c);
}

__device__ __forceinline__ unsigned long long shfl_xor_u64(unsigned long long v, int m) {
    unsigned lo = (unsigned)v, hi = (unsigned)(v >> 32);
    lo = (unsigned)__shfl_xor((int)lo, m, 64);
    hi = (unsigned)__shfl_xor((int)hi, m, 64);
    return ((unsigned long long)hi << 32) | lo;
}

// ---------------- fp32 -> fp16 convert (x) ----------------
__global__ void cvt_kernel(const float* __restrict__ src, _Float16* __restrict__ dst, int n4) {
    int i = blockIdx.x * 256 + threadIdx.x;
    if (i >= n4) return;
    float4 v = ((const float4*)src)[i];
    half4v h;
    h[0] = (_Float16)v.x; h[1] = (_Float16)v.y;
    h[2] = (_Float16)v.z; h[3] = (_Float16)v.w;
    ((half4v*)dst)[i] = h;
}

// ---------------- w: fp32->fp16 convert fused with 0.5*||w_c||^2 ----------------
__global__ __launch_bounds__(192) void cvtw_wn2_kernel(
    const float* __restrict__ w, _Float16* __restrict__ wh, float* __restrict__ wn2) {
    const int c = blockIdx.x;
    const int t = threadIdx.x;                   // 0..191 (one float4 each)
    const size_t i4 = (size_t)c * 192 + t;
    float4 v = ((const float4*)w)[i4];
    half4v h;
    h[0] = (_Float16)v.x; h[1] = (_Float16)v.y;
    h[2] = (_Float16)v.z; h[3] = (_Float16)v.w;
    ((half4v*)wh)[i4] = h;
    float s = v.x * v.x + v.y * v.y + v.z * v.z + v.w * v.w;
    #pragma unroll
    for (int off = 32; off; off >>= 1) s += __shfl_down(s, off, 64);
    __shared__ float p[3];
    if ((t & 63) == 0) p[t >> 6] = s;
    __syncthreads();
    if (t == 0) wn2[c] = 0.5f * (p[0] + p[1] + p[2]);
}

// ---------------- MFMA BMU v6: v2 skeleton (proven 140us) + XCD locality remap ----
// best_b = argmax_c (x_b.w_c - 0.5||w_c||^2).
// 256x256 tile, BK=32, 8 waves (2M x 4N), per-wave 128x64, 16x16x32 MFMA,
// acc[8][4] f32x4. 4-deep ring, ONE barrier per K-tile, counted vmcnt(8)
// (never 0 midloop), staging interleaved between MFMA clusters, compiler-
// scheduled lgkmcnt. __launch_bounds__(512,2) = 256-VGPR budget.
// Session ledger (do not re-try):
//  - v3 per-phase barrier pairs + lgkmcnt(0) pinning: 140->148us (defeats
//    compiler's fine lgkmcnt interleave; doubles barriers at 2 waves/SIMD).
//  - v4 __launch_bounds__(512,4): 128-VGPR cap -> acc spilled -> 1875us.
//  - v5 32x32x16 MFMA: bank = ps*4 (line-independent) so 32-lane fragment
//    reads are structurally 4-way conflicted (9.4M conflicts) + dependent
//    MFMA pairs -> 185us. 16x16 fragment reads are 2-way = free.
// Ring invariants: stage(t+3) (buf (t-1)&3) issued after the barrier proving
// all reads of tile t-1 consumed; vmcnt(8) at top retires tile t's 4 loads
// (12 in flight steady-state); tail drains 8->4->0.
// LDS layout: line = row>>1 (128B line = row pair), phys slot =
// ((row&1)<<2 | q) ^ (line&7); global source pre-swizzled so the linear
// global_load_lds dest (wave-uniform base + lane*16B) matches.
#define BMU_NT 24   // 768 / 32

__global__ __launch_bounds__(512, 2) void bmu_kernel(
    const _Float16* __restrict__ xh, const _Float16* __restrict__ wh,
    const float* __restrict__ wn2, unsigned long long* __restrict__ best) {
    __shared__ _Float16 AB[4][2][8192];       // [buf][A,B][128 lines x 64 halves]
    __shared__ unsigned long long red[256];

    const int tid  = threadIdx.x;
    const int wv   = tid >> 6;
    const int lane = tid & 63;
    const int l15  = lane & 15;
    const int q    = lane >> 4;
    const int wr   = wv >> 2;        // 0..1 (M half)
    const int wc   = wv & 3;         // 0..3 (N quarter)

    // XCD-aware remap (v3/v5, measured FETCH 110->71MB): each XCD owns 8
    // w-tiles; concurrent window = 4 w-tiles x 8 x-tiles = 4.7MB vs 4MB L2.
    const int bid = blockIdx.x;      // 0..1023
    const int xcd = bid & 7;
    const int rem = bid >> 3;        // 0..127
    const int cbl = rem & 3;         // w tile (inner, 4 concurrent)
    const int bb  = (rem >> 2) & 15; // x tile (middle)
    const int cbg = rem >> 6;        // 0..1 (outer w group)
    const int cb  = xcd * 8 + cbg * 4 + cbl;
    const int b0 = bb * 256;
    const int c0 = cb * 256;

    if (tid < 256) red[tid] = 0ULL;

    // staging source decomposition (pre-swizzled global addresses).
    // round r covers lines [64r,64r+64); key (L&7) == (Ls&7) since 64%8==0.
    const int Ls = tid >> 3;         // line within round
    const int ss = tid & 7;          // phys slot == linear dest slot
    const int sl = ss ^ (Ls & 7);    // logical slot
    const int prow = 2 * Ls + (sl >> 2);     // row within 128-row round block
    const int kc8  = (sl & 3) * 8;           // k-chunk offset (halves)
    const _Float16* gA0 = xh + (size_t)(b0 + prow) * DIM + kc8;
    const _Float16* gA1 = gA0 + (size_t)128 * DIM;
    const _Float16* gB0 = wh + (size_t)(c0 + prow) * DIM + kc8;
    const _Float16* gB1 = gB0 + (size_t)128 * DIM;
    const int ldsoff = wv * 512;     // halves: wave-uniform base within a round

    // fragment LDS offsets (halves)
    int aoff[8], boff[4];
    #pragma unroll
    for (int i = 0; i < 8; ++i) {
        const int row = wr * 128 + i * 16 + l15;
        const int line = row >> 1;
        const int ps = (((row & 1) << 2) | q) ^ (line & 7);
        aoff[i] = line * 64 + ps * 8;
    }
    #pragma unroll
    for (int jj = 0; jj < 4; ++jj) {
        const int row = wc * 64 + jj * 16 + l15;
        const int line = row >> 1;
        const int ps = (((row & 1) << 2) | q) ^ (line & 7);
        boff[jj] = line * 64 + ps * 8;
    }

    floatx4 acc[8][4];
    #pragma unroll
    for (int i = 0; i < 8; ++i)
        #pragma unroll
        for (int jj = 0; jj < 4; ++jj) acc[i][jj] = (floatx4){0.f, 0.f, 0.f, 0.f};

    // prologue: stage tiles 0..2 (4 global_load_lds each per thread)
    #pragma unroll
    for (int t = 0; t < 3; ++t) {
        _Float16* A = &AB[t][0][0];
        _Float16* B = &AB[t][1][0];
        __builtin_amdgcn_global_load_lds(GPTR(gA0 + t * 32), LPTR(A + ldsoff),        16, 0, 0);
        __builtin_amdgcn_global_load_lds(GPTR(gA1 + t * 32), LPTR(A + 4096 + ldsoff), 16, 0, 0);
        __builtin_amdgcn_global_load_lds(GPTR(gB0 + t * 32), LPTR(B + ldsoff),        16, 0, 0);
        __builtin_amdgcn_global_load_lds(GPTR(gB1 + t * 32), LPTR(B + 4096 + ldsoff), 16, 0, 0);
    }

    for (int t = 0; t < BMU_NT; ++t) {
        // counted drain: own loads of tile t retired; t+1.. stay in flight
        if (t < BMU_NT - 2)       asm volatile("s_waitcnt vmcnt(8)" ::: "memory");
        else if (t == BMU_NT - 2) asm volatile("s_waitcnt vmcnt(4)" ::: "memory");
        else                      asm volatile("s_waitcnt vmcnt(0)" ::: "memory");
        __builtin_amdgcn_s_barrier();
        asm volatile("" ::: "memory");   // no LDS-read hoisting above the barrier

        const _Float16* A = &AB[t & 3][0][0];
        const _Float16* B = &AB[t & 3][1][0];
        const bool more = (t + 3) < BMU_NT;
        _Float16* An = &AB[(t + 3) & 3][0][0];
        _Float16* Bn = &AB[(t + 3) & 3][1][0];
        const int t3 = (t + 3) * 32;

        half8 af[8], bf[4];
        // phase 0: i0-3 x j0-1
        #pragma unroll
        for (int i = 0; i < 4; ++i) af[i] = *(const half8*)(A + aoff[i]);
        bf[0] = *(const half8*)(B + boff[0]);
        bf[1] = *(const half8*)(B + boff[1]);
        if (more) __builtin_amdgcn_global_load_lds(GPTR(gA0 + t3), LPTR(An + ldsoff), 16, 0, 0);
        __builtin_amdgcn_s_setprio(1);
        #pragma unroll
        for (int i = 0; i < 4; ++i) {
            acc[i][0] = __builtin_amdgcn_mfma_f32_16x16x32_f16(af[i], bf[0], acc[i][0], 0, 0, 0);
            acc[i][1] = __builtin_amdgcn_mfma_f32_16x16x32_f16(af[i], bf[1], acc[i][1], 0, 0, 0);
        }
        __builtin_amdgcn_s_setprio(0);
        // phase 1: i4-7 x j0-1
        #pragma unroll
        for (int i = 4; i < 8; ++i) af[i] = *(const half8*)(A + aoff[i]);
        if (more) __builtin_amdgcn_global_load_lds(GPTR(gA1 + t3), LPTR(An + 4096 + ldsoff), 16, 0, 0);
        __builtin_amdgcn_s_setprio(1);
        #pragma unroll
        for (int i = 4; i < 8; ++i) {
            acc[i][0] = __builtin_amdgcn_mfma_f32_16x16x32_f16(af[i], bf[0], acc[i][0], 0, 0, 0);
            acc[i][1] = __builtin_amdgcn_mfma_f32_16x16x32_f16(af[i], bf[1], acc[i][1], 0, 0, 0);
        }
        __builtin_amdgcn_s_setprio(0);
        // phase 2: i4-7 x j2-3
        bf[2] = *(const half8*)(B + boff[2]);
        bf[3] = *(const half8*)(B + boff[3]);
        if (more) __builtin_amdgcn_global_load_lds(GPTR(gB0 + t3), LPTR(Bn + ldsoff), 16, 0, 0);
        __builtin_amdgcn_s_setprio(1);
        #pragma unroll
        for (int i = 4; i < 8; ++i) {
            acc[i][2] = __builtin_amdgcn_mfma_f32_16x16x32_f16(af[i], bf[2], acc[i][2], 0, 0, 0);
            acc[i][3] = __builtin_amdgcn_mfma_f32_16x16x32_f16(af[i], bf[3], acc[i][3], 0, 0, 0);
        }
        __builtin_amdgcn_s_setprio(0);
        // phase 3: i0-3 x j2-3
        if (more) __builtin_amdgcn_global_load_lds(GPTR(gB1 + t3), LPTR(Bn + 4096 + ldsoff), 16, 0, 0);
        __builtin_amdgcn_s_setprio(1);
        #pragma unroll
        for (int i = 0; i < 4; ++i) {
            acc[i][2] = __builtin_amdgcn_mfma_f32_16x16x32_f16(af[i], bf[2], acc[i][2], 0, 0, 0);
            acc[i][3] = __builtin_amdgcn_mfma_f32_16x16x32_f16(af[i], bf[3], acc[i][3], 0, 0, 0);
        }
        __builtin_amdgcn_s_setprio(0);
    }

    // ---------------- argmax epilogue ----------------
    float wnj[4];
    #pragma unroll
    for (int jj = 0; jj < 4; ++jj) wnj[jj] = wn2[c0 + wc * 64 + jj * 16 + l15];

    #pragma unroll
    for (int i = 0; i < 8; ++i) {
        #pragma unroll
        for (int r = 0; r < 4; ++r) {
            unsigned long long m = 0ULL;
            #pragma unroll
            for (int jj = 0; jj < 4; ++jj) {
                const float s = acc[i][jj][r] - wnj[jj];
                const unsigned long long p = packScore(s, c0 + wc * 64 + jj * 16 + l15);
                if (p > m) m = p;
            }
            #pragma unroll
            for (int msk = 1; msk <= 8; msk <<= 1) {
                const unsigned long long o = shfl_xor_u64(m, msk);
                if (o > m) m = o;
            }
            if (l15 == 0)
                atomicMax(&red[wr * 128 + i * 16 + q * 4 + r], m);
        }
    }
    __syncthreads();
    if (tid < 256) atomicMax(&best[b0 + tid], red[tid]);
}

// ---------------- scatter x rows into full-width G + histogram ----------------
__global__ void scatter_kernel(const unsigned long long* __restrict__ best,
                               const float* __restrict__ x,
                               float* __restrict__ G, float* __restrict__ cnt) {
    const int b = blockIdx.x;
    const int c = (int)(~(unsigned)(best[b] & 0xFFFFFFFFULL));
    float* gr = G + (size_t)c * DIM;
    const float* xr = x + (size_t)b * DIM;
    #pragma unroll
    for (int u = 0; u < 3; ++u) {
        const int d = threadIdx.x + u * 256;
        atomicAdd(&gr[d], xr[d]);
    }
    if (threadIdx.x == 0) atomicAdd(&cnt[c], 1.0f);
}

#define EP 136   // Es pitch (halves)
#define BP 40    // Bs pitch (halves)

// ---- conv pass A (MFMA): H[(i,jc), d] = sum_j E[jc,j] * G[(i,j), d]; H fp16 packed into G rows ----
__global__ __launch_bounds__(256) void convA_kernel(
    const float* G, _Float16* Hh, const int* __restrict__ itp) {
    __shared__ _Float16 Es[128 * EP];   // E fp16, later reused as fp32 bounce
    __shared__ _Float16 Bs[128 * BP];
    const int d0 = blockIdx.x * 128;    // 0..5
    const int ib = blockIdx.y;          // 0..127
    const int tid = threadIdx.x;
    const int wv = tid >> 6, lane = tid & 63;
    const int l15 = lane & 15, q = lane >> 4;
    const int mrow = (wv >> 1) * 64, ncol = (wv & 1) * 64;

    {   // compute E tile in LDS on the fly
        const float decay = 1.f - (float)(*itp) / NITER_F;
        const float sig = SIGMA0 * decay;
        const float inv = -1.f / (sig * sig);
        const int row = tid >> 1, hh = tid & 1;
        _Float16* dst = Es + row * EP + hh * 64;
        #pragma unroll
        for (int u = 0; u < 64; ++u) {
            const float dd = (float)(row - hh * 64 - u);
            dst[u] = (_Float16)__expf(dd * dd * inv);
        }
    }

    floatx4 acc[4][4];
    #pragma unroll
    for (int i = 0; i < 4; ++i)
        #pragma unroll
        for (int j = 0; j < 4; ++j) acc[i][j] = (floatx4){0.f, 0.f, 0.f, 0.f};

    const int dpo = (tid & 15) * 8;     // d-octet within 128
    const int rsel = tid >> 4;          // 0..15 row selector
    for (int k0 = 0; k0 < 128; k0 += 32) {
        __syncthreads();
        #pragma unroll
        for (int s = 0; s < 2; ++s) {   // coalesced: 16 lanes read one row's 512B
            const int j = k0 + s * 16 + rsel;
            const float* r = G + (size_t)(ib * 128 + j) * DIM + d0 + dpo;
            float4 a0 = *(const float4*)r, a1 = *(const float4*)(r + 4);
            float va[8] = {a0.x, a0.y, a0.z, a0.w, a1.x, a1.y, a1.z, a1.w};
            #pragma unroll
            for (int u = 0; u < 8; ++u)
                Bs[(dpo + u) * BP + (s * 16 + rsel)] = (_Float16)va[u];
        }
        __syncthreads();
        half8 af[4], bf[4];
        #pragma unroll
        for (int i = 0; i < 4; ++i)
            af[i] = *(const half8*)(Es + (mrow + i * 16 + l15) * EP + k0 + q * 8);
        #pragma unroll
        for (int j = 0; j < 4; ++j)
            bf[j] = *(const half8*)(Bs + (ncol + j * 16 + l15) * BP + q * 8);
        #pragma unroll
        for (int i = 0; i < 4; ++i)
            #pragma unroll
            for (int j = 0; j < 4; ++j)
                acc[i][j] = __builtin_amdgcn_mfma_f32_16x16x32_f16(af[i], bf[j], acc[i][j], 0, 0, 0);
    }
    __syncthreads();
    // fp32 bounce epilogue in 2 chunks of 64 rows (m = jc), write H fp16 chunk-packed
    float* Ebf = (float*)Es;            // [64][132] floats = 33792 B <= 34816
    #pragma unroll
    for (int ch = 0; ch < 2; ++ch) {
        if ((wv >> 1) == ch) {
            #pragma unroll
            for (int i = 0; i < 4; ++i)
                #pragma unroll
                for (int j = 0; j < 4; ++j)
                    #pragma unroll
                    for (int r = 0; r < 4; ++r)
                        Ebf[(i * 16 + q * 4 + r) * 132 + ncol + j * 16 + l15] = acc[i][j][r];
        }
        __syncthreads();
        {
            const int row = tid >> 2, seg = tid & 3;    // 64 rows x 4 segs of 32
            const int m = ch * 64 + row;                // jc
            // H chunk-packed: half-index = c*1536 + d0*2 + dl
            _Float16* hp = Hh + (size_t)(ib * 128 + m) * 1536 + d0 * 2 + seg * 32;
            #pragma unroll
            for (int u = 0; u < 4; ++u) {
                const float* sp = Ebf + row * 132 + seg * 32 + u * 8;
                half8 hv;
                #pragma unroll
                for (int e = 0; e < 8; ++e) hv[e] = (_Float16)sp[e];
                *(half8*)(hp + u * 8) = hv;
            }
        }
        __syncthreads();
    }
}

// ---- conv pass B (MFMA) + fused S-conv + epilogue:
//      out[(ic,jc),d] = w*(1-a*S[ic,jc]) + a * sum_i E[ic,i] H[(i,jc),d]
__global__ __launch_bounds__(256) void convB_kernel(
    const _Float16* Hh, const float* __restrict__ w, const float* __restrict__ cnt,
    const int* __restrict__ itp, float* __restrict__ out) {
    __shared__ _Float16 Es[128 * EP];
    __shared__ _Float16 Bs[128 * BP];
    __shared__ float cntHs[128];
    __shared__ float Ss[128];
    const int d0 = blockIdx.x * 128;    // 0..5
    const int jc = blockIdx.y;          // 0..127
    const int tid = threadIdx.x;
    const int wv = tid >> 6, lane = tid & 63;
    const int l15 = lane & 15, q = lane >> 4;
    const int mrow = (wv >> 1) * 64, ncol = (wv & 1) * 64;
    const float decay = 1.f - (float)(*itp) / NITER_F;
    const float alpha = ALPHA0 * decay;
    const float sig = SIGMA0 * decay;
    const float inv = -1.f / (sig * sig);

    // count-conv for this jc column (S[ic] for all ic), fp32
    if (tid < 128) {
        float s = 0.f;
        for (int j = 0; j < 128; ++j) {
            const float dd = (float)(jc - j);
            s += __expf(dd * dd * inv) * cnt[tid * 128 + j];
        }
        cntHs[tid] = s;
    }
    {   // compute E tile in LDS
        const int row = tid >> 1, hh = tid & 1;
        _Float16* dst = Es + row * EP + hh * 64;
        #pragma unroll
        for (int u = 0; u < 64; ++u) {
            const float dd = (float)(row - hh * 64 - u);
            dst[u] = (_Float16)__expf(dd * dd * inv);
        }
    }
    __syncthreads();
    if (tid < 128) {
        float s = 0.f;
        for (int i = 0; i < 128; ++i) {
            const float dd = (float)(tid - i);
            s += __expf(dd * dd * inv) * cntHs[i];
        }
        Ss[tid] = s;
    }

    floatx4 acc[4][4];
    #pragma unroll
    for (int i = 0; i < 4; ++i)
        #pragma unroll
        for (int j = 0; j < 4; ++j) acc[i][j] = (floatx4){0.f, 0.f, 0.f, 0.f};

    const int dpo = (tid & 15) * 8;
    const int rsel = tid >> 4;
    for (int k0 = 0; k0 < 128; k0 += 32) {
        __syncthreads();
        #pragma unroll
        for (int s = 0; s < 2; ++s) {   // coalesced: 16 lanes read one row's 256B chunk
            const int i = k0 + s * 16 + rsel;
            const half8 v = *(const half8*)(Hh + (size_t)(i * 128 + jc) * 1536 + d0 * 2 + dpo);
            #pragma unroll
            for (int u = 0; u < 8; ++u)
                Bs[(dpo + u) * BP + (s * 16 + rsel)] = v[u];
        }
        __syncthreads();
        half8 af[4], bf[4];
        #pragma unroll
        for (int i = 0; i < 4; ++i)
            af[i] = *(const half8*)(Es + (mrow + i * 16 + l15) * EP + k0 + q * 8);
        #pragma unroll
        for (int j = 0; j < 4; ++j)
            bf[j] = *(const half8*)(Bs + (ncol + j * 16 + l15) * BP + q * 8);
        #pragma unroll
        for (int i = 0; i < 4; ++i)
            #pragma unroll
            for (int j = 0; j < 4; ++j)
                acc[i][j] = __builtin_amdgcn_mfma_f32_16x16x32_f16(af[i], bf[j], acc[i][j], 0, 0, 0);
    }
    __syncthreads();
    // fused epilogue: fp32 bounce in 2 chunks of 64 rows (m = ic)
    float* Ebf = (float*)Es;            // [64][132] floats
    #pragma unroll
    for (int ch = 0; ch < 2; ++ch) {
        if ((wv >> 1) == ch) {
            #pragma unroll
            for (int i = 0; i < 4; ++i)
                #pragma unroll
                for (int j = 0; j < 4; ++j)
                    #pragma unroll
                    for (int r = 0; r < 4; ++r)
                        Ebf[(i * 16 + q * 4 + r) * 132 + ncol + j * 16 + l15] = acc[i][j][r];
        }
        __syncthreads();
        {
            const int row = tid >> 2, seg = tid & 3;    // 64 rows x 4 segs of 32 floats
            const int m = ch * 64 + row;                // ic
            const int c = m * 128 + jc;
            const float scl = 1.f - alpha * Ss[m];
            const size_t g = (size_t)c * DIM + d0 + seg * 32;
            #pragma unroll
            for (int u = 0; u < 8; ++u) {
                float4 wv4 = *(const float4*)(w + g + u * 4);
                float4 t4  = *(const float4*)(Ebf + row * 132 + seg * 32 + u * 4);
                float4 o;
                o.x = wv4.x * scl + alpha * t4.x;
                o.y = wv4.y * scl + alpha * t4.y;
                o.z = wv4.z * scl + alpha * t4.z;
                o.w = wv4.w * scl + alpha * t4.w;
                *(float4*)(out + g + u * 4) = o;
            }
        }
        __syncthreads();
    }
}

extern "C" void kernel_launch(void* const* d_in, const int* in_sizes, int n_in,
                              void* d_out, int out_size, void* d_ws, size_t ws_size,
                              hipStream_t stream) {
    const float* x  = (const float*)d_in[0];   // [4096, 768]
    const float* w  = (const float*)d_in[1];   // [16384, 768]
    const int* itp  = (const int*)d_in[2];     // scalar it
    float* out = (float*)d_out;                // [16384, 768]
    char* ws = (char*)d_ws;

    _Float16* xh = (_Float16*)(ws + XH_OFF);
    _Float16* wh = (_Float16*)(ws + WH_OFF);
    float*    G  = (float*)(ws + G_OFF);       // aliases xh/wh, used post-bmu
    _Float16* Hh = (_Float16*)(ws + G_OFF);    // H fp16 chunk-packed inside G rows
    unsigned long long* best = (unsigned long long*)(ws + BEST_OFF);
    float* cnt  = (float*)(ws + CNT_OFF);
    float* wn2  = (float*)(ws + WN2_OFF);

    hipMemsetAsync(ws + BEST_OFF, 0, BEST_BYTES + CNT_BYTES, stream);

    cvt_kernel<<<(BS * DIM / 4 + 255) / 256, 256, 0, stream>>>(x, xh, BS * DIM / 4);
    cvtw_wn2_kernel<<<COMPS, 192, 0, stream>>>(w, wh, wn2);

    // 1024 blocks = 16 b-tiles x 64 c-tiles (XCD-remapped inside the kernel)
    bmu_kernel<<<dim3(1024), 512, 0, stream>>>(xh, wh, wn2, best);

    // xh/wh dead -> zero full G (stream-ordered after bmu)
    hipMemsetAsync(ws + G_OFF, 0, G_BYTES, stream);
    scatter_kernel<<<BS, 256, 0, stream>>>(best, x, G, cnt);

    // pass A: H fp16 (chunk-packed into G storage)
    convA_kernel<<<dim3(6, 128), 256, 0, stream>>>(G, Hh, itp);
    // pass B + count-conv + epilogue -> d_out
    convB_kernel<<<dim3(6, 128), 256, 0, stream>>>(Hh, w, cnt, itp, out);
}

// Round 12
// 315.609 us; speedup vs baseline: 6.4803x; 1.0662x over previous
//
#include <hip/hip_runtime.h>
#include <hip/hip_fp16.h>
#include <cstdint>
#include <cstddef>

// ---------------- problem constants ----------------
#define BS    4096
#define DIM   768
#define GM    128
#define GN    128
#define COMPS (GM * GN)          // 16384
#define NITER_F 1000.0f
#define ALPHA0  0.3f
#define SIGMA0  64.0f            // max(M,N)/2

typedef _Float16 half8  __attribute__((ext_vector_type(8)));
typedef _Float16 half4v __attribute__((ext_vector_type(4)));
typedef _Float16 half2v __attribute__((ext_vector_type(2)));
typedef float    floatx4 __attribute__((ext_vector_type(4)));

// ---------------- workspace layout (bytes) ----------------
// Phase 1 (pre-bmu): xh fp16 @0 (6.3MB), wh fp16 @8MB (25.2MB).
// Phase 2 (post-bmu): G fp16 @0 (25.2MB) — aliases xh + wh[0..17MB], both
// dead after bmu. NOTE: scatter reads the ORIGINAL fp32 x (input buffer),
// NOT xh — xh is inside G's footprint and is zeroed by the G memset.
// H fp16 (same geometry) is written IN-PLACE over G by convA: block (d0,ib)
// reads G rows [ib*128,+128) cols [d0,+128) in its k-loop, then writes H to
// the same rows/cols after all reads — race-free in-block, disjoint across
// blocks. Tails (best/cnt/wn2) stay at the legacy >50.33MB offsets (above
// wh's end, which bmu reads while writing best).
#define XH_OFF    0UL
#define WH_OFF    (8UL * 1024UL * 1024UL)
#define G_OFF     0UL
#define GH_BYTES  ((size_t)COMPS * DIM * 2UL)     // 25,165,824 (fp16 G/H)
#define BEST_OFF  ((size_t)COMPS * DIM * 4UL)     // 50,331,648 (legacy offset, > wh end)
#define BEST_BYTES ((size_t)BS * 8UL)             // 32 KB
#define CNT_OFF   (BEST_OFF + BEST_BYTES)
#define CNT_BYTES ((size_t)COMPS * 4UL)           // 64 KB
#define WN2_OFF   (CNT_OFF + CNT_BYTES)

#define GPTR(p) ((const __attribute__((address_space(1))) void*)(p))
#define LPTR(p) ((__attribute__((address_space(3))) void*)(p))

// pack (score, index) so that u64 max == (max score, min index on ties)
__device__ __forceinline__ unsigned long long packScore(float s, int c) {
    unsigned u = __float_as_uint(s);
    u = (u & 0x80000000u) ? ~u : (u | 0x80000000u);   // order-preserving map
    return ((unsigned long long)u << 32) | (unsigned)(~(unsigned)c);
}

__device__ __forceinline__ unsigned long long shfl_xor_u64(unsigned long long v, int m) {
    unsigned lo = (unsigned)v, hi = (unsigned)(v >> 32);
    lo = (unsigned)__shfl_xor((int)lo, m, 64);
    hi = (unsigned)__shfl_xor((int)hi, m, 64);
    return ((unsigned long long)hi << 32) | lo;
}

// packed fp16 atomic add — ROCm headers lack the __half2 atomicAdd overload;
// emit the gfx950 instruction directly (no return value needed).
__device__ __forceinline__ void atomicAddPkF16(_Float16* p, half2v v) {
    asm volatile("global_atomic_pk_add_f16 %0, %1, off" : : "v"(p), "v"(v) : "memory");
}

// ---------------- fp32 -> fp16 convert (x) ----------------
__global__ void cvt_kernel(const float* __restrict__ src, _Float16* __restrict__ dst, int n4) {
    int i = blockIdx.x * 256 + threadIdx.x;
    if (i >= n4) return;
    float4 v = ((const float4*)src)[i];
    half4v h;
    h[0] = (_Float16)v.x; h[1] = (_Float16)v.y;
    h[2] = (_Float16)v.z; h[3] = (_Float16)v.w;
    ((half4v*)dst)[i] = h;
}

// ---------------- w: fp32->fp16 convert fused with 0.5*||w_c||^2 ----------------
__global__ __launch_bounds__(192) void cvtw_wn2_kernel(
    const float* __restrict__ w, _Float16* __restrict__ wh, float* __restrict__ wn2) {
    const int c = blockIdx.x;
    const int t = threadIdx.x;                   // 0..191 (one float4 each)
    const size_t i4 = (size_t)c * 192 + t;
    float4 v = ((const float4*)w)[i4];
    half4v h;
    h[0] = (_Float16)v.x; h[1] = (_Float16)v.y;
    h[2] = (_Float16)v.z; h[3] = (_Float16)v.w;
    ((half4v*)wh)[i4] = h;
    float s = v.x * v.x + v.y * v.y + v.z * v.z + v.w * v.w;
    #pragma unroll
    for (int off = 32; off; off >>= 1) s += __shfl_down(s, off, 64);
    __shared__ float p[3];
    if ((t & 63) == 0) p[t >> 6] = s;
    __syncthreads();
    if (t == 0) wn2[c] = 0.5f * (p[0] + p[1] + p[2]);
}

// ---------------- MFMA BMU v6 (UNCHANGED, verified 138.5us / MfmaUtil 32 / 0 conflicts) ----
// v2 skeleton + XCD locality remap. Session ledger (do not re-try):
//  - v3 per-phase barrier pairs + lgkmcnt(0) pinning: 140->148us.
//  - v4 __launch_bounds__(512,4): 128-VGPR cap -> acc spill -> 1875us.
//  - v5 32x32x16 MFMA: bank = ps*4 (line-independent) -> structural 4-way
//    conflict on 32-lane fragment reads (9.4M) -> 185us.
#define BMU_NT 24   // 768 / 32

__global__ __launch_bounds__(512, 2) void bmu_kernel(
    const _Float16* __restrict__ xh, const _Float16* __restrict__ wh,
    const float* __restrict__ wn2, unsigned long long* __restrict__ best) {
    __shared__ _Float16 AB[4][2][8192];       // [buf][A,B][128 lines x 64 halves]
    __shared__ unsigned long long red[256];

    const int tid  = threadIdx.x;
    const int wv   = tid >> 6;
    const int lane = tid & 63;
    const int l15  = lane & 15;
    const int q    = lane >> 4;
    const int wr   = wv >> 2;        // 0..1 (M half)
    const int wc   = wv & 3;         // 0..3 (N quarter)

    // XCD-aware remap (measured FETCH 110->71MB): each XCD owns 8 w-tiles;
    // concurrent window = 4 w-tiles x 8 x-tiles = 4.7MB vs 4MB L2.
    const int bid = blockIdx.x;      // 0..1023
    const int xcd = bid & 7;
    const int rem = bid >> 3;        // 0..127
    const int cbl = rem & 3;         // w tile (inner, 4 concurrent)
    const int bb  = (rem >> 2) & 15; // x tile (middle)
    const int cbg = rem >> 6;        // 0..1 (outer w group)
    const int cb  = xcd * 8 + cbg * 4 + cbl;
    const int b0 = bb * 256;
    const int c0 = cb * 256;

    if (tid < 256) red[tid] = 0ULL;

    // staging source decomposition (pre-swizzled global addresses).
    const int Ls = tid >> 3;         // line within round
    const int ss = tid & 7;          // phys slot == linear dest slot
    const int sl = ss ^ (Ls & 7);    // logical slot
    const int prow = 2 * Ls + (sl >> 2);     // row within 128-row round block
    const int kc8  = (sl & 3) * 8;           // k-chunk offset (halves)
    const _Float16* gA0 = xh + (size_t)(b0 + prow) * DIM + kc8;
    const _Float16* gA1 = gA0 + (size_t)128 * DIM;
    const _Float16* gB0 = wh + (size_t)(c0 + prow) * DIM + kc8;
    const _Float16* gB1 = gB0 + (size_t)128 * DIM;
    const int ldsoff = wv * 512;     // halves: wave-uniform base within a round

    // fragment LDS offsets (halves)
    int aoff[8], boff[4];
    #pragma unroll
    for (int i = 0; i < 8; ++i) {
        const int row = wr * 128 + i * 16 + l15;
        const int line = row >> 1;
        const int ps = (((row & 1) << 2) | q) ^ (line & 7);
        aoff[i] = line * 64 + ps * 8;
    }
    #pragma unroll
    for (int jj = 0; jj < 4; ++jj) {
        const int row = wc * 64 + jj * 16 + l15;
        const int line = row >> 1;
        const int ps = (((row & 1) << 2) | q) ^ (line & 7);
        boff[jj] = line * 64 + ps * 8;
    }

    floatx4 acc[8][4];
    #pragma unroll
    for (int i = 0; i < 8; ++i)
        #pragma unroll
        for (int jj = 0; jj < 4; ++jj) acc[i][jj] = (floatx4){0.f, 0.f, 0.f, 0.f};

    // prologue: stage tiles 0..2 (4 global_load_lds each per thread)
    #pragma unroll
    for (int t = 0; t < 3; ++t) {
        _Float16* A = &AB[t][0][0];
        _Float16* B = &AB[t][1][0];
        __builtin_amdgcn_global_load_lds(GPTR(gA0 + t * 32), LPTR(A + ldsoff),        16, 0, 0);
        __builtin_amdgcn_global_load_lds(GPTR(gA1 + t * 32), LPTR(A + 4096 + ldsoff), 16, 0, 0);
        __builtin_amdgcn_global_load_lds(GPTR(gB0 + t * 32), LPTR(B + ldsoff),        16, 0, 0);
        __builtin_amdgcn_global_load_lds(GPTR(gB1 + t * 32), LPTR(B + 4096 + ldsoff), 16, 0, 0);
    }

    for (int t = 0; t < BMU_NT; ++t) {
        // counted drain: own loads of tile t retired; t+1.. stay in flight
        if (t < BMU_NT - 2)       asm volatile("s_waitcnt vmcnt(8)" ::: "memory");
        else if (t == BMU_NT - 2) asm volatile("s_waitcnt vmcnt(4)" ::: "memory");
        else                      asm volatile("s_waitcnt vmcnt(0)" ::: "memory");
        __builtin_amdgcn_s_barrier();
        asm volatile("" ::: "memory");   // no LDS-read hoisting above the barrier

        const _Float16* A = &AB[t & 3][0][0];
        const _Float16* B = &AB[t & 3][1][0];
        const bool more = (t + 3) < BMU_NT;
        _Float16* An = &AB[(t + 3) & 3][0][0];
        _Float16* Bn = &AB[(t + 3) & 3][1][0];
        const int t3 = (t + 3) * 32;

        half8 af[8], bf[4];
        // phase 0: i0-3 x j0-1
        #pragma unroll
        for (int i = 0; i < 4; ++i) af[i] = *(const half8*)(A + aoff[i]);
        bf[0] = *(const half8*)(B + boff[0]);
        bf[1] = *(const half8*)(B + boff[1]);
        if (more) __builtin_amdgcn_global_load_lds(GPTR(gA0 + t3), LPTR(An + ldsoff), 16, 0, 0);
        __builtin_amdgcn_s_setprio(1);
        #pragma unroll
        for (int i = 0; i < 4; ++i) {
            acc[i][0] = __builtin_amdgcn_mfma_f32_16x16x32_f16(af[i], bf[0], acc[i][0], 0, 0, 0);
            acc[i][1] = __builtin_amdgcn_mfma_f32_16x16x32_f16(af[i], bf[1], acc[i][1], 0, 0, 0);
        }
        __builtin_amdgcn_s_setprio(0);
        // phase 1: i4-7 x j0-1
        #pragma unroll
        for (int i = 4; i < 8; ++i) af[i] = *(const half8*)(A + aoff[i]);
        if (more) __builtin_amdgcn_global_load_lds(GPTR(gA1 + t3), LPTR(An + 4096 + ldsoff), 16, 0, 0);
        __builtin_amdgcn_s_setprio(1);
        #pragma unroll
        for (int i = 4; i < 8; ++i) {
            acc[i][0] = __builtin_amdgcn_mfma_f32_16x16x32_f16(af[i], bf[0], acc[i][0], 0, 0, 0);
            acc[i][1] = __builtin_amdgcn_mfma_f32_16x16x32_f16(af[i], bf[1], acc[i][1], 0, 0, 0);
        }
        __builtin_amdgcn_s_setprio(0);
        // phase 2: i4-7 x j2-3
        bf[2] = *(const half8*)(B + boff[2]);
        bf[3] = *(const half8*)(B + boff[3]);
        if (more) __builtin_amdgcn_global_load_lds(GPTR(gB0 + t3), LPTR(Bn + ldsoff), 16, 0, 0);
        __builtin_amdgcn_s_setprio(1);
        #pragma unroll
        for (int i = 4; i < 8; ++i) {
            acc[i][2] = __builtin_amdgcn_mfma_f32_16x16x32_f16(af[i], bf[2], acc[i][2], 0, 0, 0);
            acc[i][3] = __builtin_amdgcn_mfma_f32_16x16x32_f16(af[i], bf[3], acc[i][3], 0, 0, 0);
        }
        __builtin_amdgcn_s_setprio(0);
        // phase 3: i0-3 x j2-3
        if (more) __builtin_amdgcn_global_load_lds(GPTR(gB1 + t3), LPTR(Bn + 4096 + ldsoff), 16, 0, 0);
        __builtin_amdgcn_s_setprio(1);
        #pragma unroll
        for (int i = 0; i < 4; ++i) {
            acc[i][2] = __builtin_amdgcn_mfma_f32_16x16x32_f16(af[i], bf[2], acc[i][2], 0, 0, 0);
            acc[i][3] = __builtin_amdgcn_mfma_f32_16x16x32_f16(af[i], bf[3], acc[i][3], 0, 0, 0);
        }
        __builtin_amdgcn_s_setprio(0);
    }

    // ---------------- argmax epilogue ----------------
    float wnj[4];
    #pragma unroll
    for (int jj = 0; jj < 4; ++jj) wnj[jj] = wn2[c0 + wc * 64 + jj * 16 + l15];

    #pragma unroll
    for (int i = 0; i < 8; ++i) {
        #pragma unroll
        for (int r = 0; r < 4; ++r) {
            unsigned long long m = 0ULL;
            #pragma unroll
            for (int jj = 0; jj < 4; ++jj) {
                const float s = acc[i][jj][r] - wnj[jj];
                const unsigned long long p = packScore(s, c0 + wc * 64 + jj * 16 + l15);
                if (p > m) m = p;
            }
            #pragma unroll
            for (int msk = 1; msk <= 8; msk <<= 1) {
                const unsigned long long o = shfl_xor_u64(m, msk);
                if (o > m) m = o;
            }
            if (l15 == 0)
                atomicMax(&red[wr * 128 + i * 16 + q * 4 + r], m);
        }
    }
    __syncthreads();
    if (tid < 256) atomicMax(&best[b0 + tid], red[tid]);
}

// ---------------- scatter x rows into fp16 G (packed half2 atomics) + histogram ----------------
// Reads the ORIGINAL fp32 x (not xh: xh is inside G's footprint and zeroed).
__global__ void scatter_kernel(const unsigned long long* __restrict__ best,
                               const float* __restrict__ x,
                               _Float16* __restrict__ Gh, float* __restrict__ cnt) {
    const int b = blockIdx.x;
    const int c = (int)(~(unsigned)(best[b] & 0xFFFFFFFFULL));
    _Float16* gr = Gh + (size_t)c * DIM;
    const float2* xr = (const float2*)(x + (size_t)b * DIM);
    #pragma unroll
    for (int u = 0; u < 2; ++u) {
        const int d = threadIdx.x + u * 192;   // 384 half2 = 768 halves
        const float2 v = xr[d];
        half2v h;
        h[0] = (_Float16)v.x; h[1] = (_Float16)v.y;
        atomicAddPkF16(gr + d * 2, h);         // global_atomic_pk_add_f16
    }
    if (threadIdx.x == 0) atomicAdd(&cnt[c], 1.0f);
}

#define EP 136   // Es pitch (halves)
#define BP 40    // Bs pitch (halves)
// Bs write conflict fix: writes put rows d=8k+u at a fixed col -> bank
// (20u + col/2) is k-independent = 16-way conflict; no 16B-aligned pitch
// fixes it (4*BP = 0 mod 32 for any BP%8==0). Octet-preserving col swizzle:
// store col' = col ^ ((k&3)<<3) (k = (d>>3)&15) -> 4-way writes; reads use
// q' = q ^ ((row>>3)&3), verified still exactly 2 lanes/bank (free).

// ---- conv pass A (MFMA): H[(i,jc), d] = sum_j E[jc,j] * G[(i,j), d]; fp16 G, H in-place ----
__global__ __launch_bounds__(256) void convA_kernel(
    const _Float16* Gh, _Float16* Hh, const int* __restrict__ itp) {
    __shared__ _Float16 Es[128 * EP];   // E fp16, later reused as fp32 bounce
    __shared__ _Float16 Bs[128 * BP];
    const int d0 = blockIdx.x * 128;    // 0..5
    const int ib = blockIdx.y;          // 0..127
    const int tid = threadIdx.x;
    const int wv = tid >> 6, lane = tid & 63;
    const int l15 = lane & 15, q = lane >> 4;
    const int mrow = (wv >> 1) * 64, ncol = (wv & 1) * 64;

    {   // compute E tile in LDS on the fly
        const float decay = 1.f - (float)(*itp) / NITER_F;
        const float sig = SIGMA0 * decay;
        const float inv = -1.f / (sig * sig);
        const int row = tid >> 1, hh = tid & 1;
        _Float16* dst = Es + row * EP + hh * 64;
        #pragma unroll
        for (int u = 0; u < 64; ++u) {
            const float dd = (float)(row - hh * 64 - u);
            dst[u] = (_Float16)__expf(dd * dd * inv);
        }
    }

    floatx4 acc[4][4];
    #pragma unroll
    for (int i = 0; i < 4; ++i)
        #pragma unroll
        for (int j = 0; j < 4; ++j) acc[i][j] = (floatx4){0.f, 0.f, 0.f, 0.f};

    const int dpo = (tid & 15) * 8;     // d-octet within 128
    const int rsel = tid >> 4;          // 0..15 row selector
    const int wsw = ((tid & 15) & 3) << 3;   // write col-swizzle = (k&3)<<3
    for (int k0 = 0; k0 < 128; k0 += 32) {
        __syncthreads();
        #pragma unroll
        for (int s = 0; s < 2; ++s) {   // coalesced: 16 lanes read one row's 256B
            const int j = k0 + s * 16 + rsel;
            const half8 v = *(const half8*)(Gh + (size_t)(ib * 128 + j) * DIM + d0 + dpo);
            #pragma unroll
            for (int u = 0; u < 8; ++u)
                Bs[(dpo + u) * BP + ((s * 16 + rsel) ^ wsw)] = v[u];
        }
        __syncthreads();
        half8 af[4], bf[4];
        #pragma unroll
        for (int i = 0; i < 4; ++i)
            af[i] = *(const half8*)(Es + (mrow + i * 16 + l15) * EP + k0 + q * 8);
        #pragma unroll
        for (int j = 0; j < 4; ++j) {
            const int row = ncol + j * 16 + l15;
            bf[j] = *(const half8*)(Bs + row * BP + ((q ^ ((row >> 3) & 3)) << 3));
        }
        #pragma unroll
        for (int i = 0; i < 4; ++i)
            #pragma unroll
            for (int j = 0; j < 4; ++j)
                acc[i][j] = __builtin_amdgcn_mfma_f32_16x16x32_f16(af[i], bf[j], acc[i][j], 0, 0, 0);
    }
    __syncthreads();
    // fp32 bounce epilogue in 2 chunks of 64 rows (m = jc); H fp16 natural
    // layout, in-place over G (this block's exact read range, reads done).
    float* Ebf = (float*)Es;            // [64][132] floats = 33792 B <= 34816
    #pragma unroll
    for (int ch = 0; ch < 2; ++ch) {
        if ((wv >> 1) == ch) {
            #pragma unroll
            for (int i = 0; i < 4; ++i)
                #pragma unroll
                for (int j = 0; j < 4; ++j)
                    #pragma unroll
                    for (int r = 0; r < 4; ++r)
                        Ebf[(i * 16 + q * 4 + r) * 132 + ncol + j * 16 + l15] = acc[i][j][r];
        }
        __syncthreads();
        {
            const int row = tid >> 2, seg = tid & 3;    // 64 rows x 4 segs of 32
            const int m = ch * 64 + row;                // jc
            _Float16* hp = Hh + (size_t)(ib * 128 + m) * DIM + d0 + seg * 32;
            #pragma unroll
            for (int u = 0; u < 4; ++u) {
                const float* sp = Ebf + row * 132 + seg * 32 + u * 8;
                half8 hv;
                #pragma unroll
                for (int e = 0; e < 8; ++e) hv[e] = (_Float16)sp[e];
                *(half8*)(hp + u * 8) = hv;
            }
        }
        __syncthreads();
    }
}

// ---- conv pass B (MFMA) + fused S-conv + epilogue:
//      out[(ic,jc),d] = w*(1-a*S[ic,jc]) + a * sum_i E[ic,i] H[(i,jc),d]
__global__ __launch_bounds__(256) void convB_kernel(
    const _Float16* Hh, const float* __restrict__ w, const float* __restrict__ cnt,
    const int* __restrict__ itp, float* __restrict__ out) {
    __shared__ _Float16 Es[128 * EP];
    __shared__ _Float16 Bs[128 * BP];
    __shared__ float cntHs[128];
    __shared__ float Ss[128];
    const int d0 = blockIdx.x * 128;    // 0..5
    const int jc = blockIdx.y;          // 0..127
    const int tid = threadIdx.x;
    const int wv = tid >> 6, lane = tid & 63;
    const int l15 = lane & 15, q = lane >> 4;
    const int mrow = (wv >> 1) * 64, ncol = (wv & 1) * 64;
    const float decay = 1.f - (float)(*itp) / NITER_F;
    const float alpha = ALPHA0 * decay;
    const float sig = SIGMA0 * decay;
    const float inv = -1.f / (sig * sig);

    // count-conv for this jc column (S[ic] for all ic), fp32
    if (tid < 128) {
        float s = 0.f;
        for (int j = 0; j < 128; ++j) {
            const float dd = (float)(jc - j);
            s += __expf(dd * dd * inv) * cnt[tid * 128 + j];
        }
        cntHs[tid] = s;
    }
    {   // compute E tile in LDS
        const int row = tid >> 1, hh = tid & 1;
        _Float16* dst = Es + row * EP + hh * 64;
        #pragma unroll
        for (int u = 0; u < 64; ++u) {
            const float dd = (float)(row - hh * 64 - u);
            dst[u] = (_Float16)__expf(dd * dd * inv);
        }
    }
    __syncthreads();
    if (tid < 128) {
        float s = 0.f;
        for (int i = 0; i < 128; ++i) {
            const float dd = (float)(tid - i);
            s += __expf(dd * dd * inv) * cntHs[i];
        }
        Ss[tid] = s;
    }

    floatx4 acc[4][4];
    #pragma unroll
    for (int i = 0; i < 4; ++i)
        #pragma unroll
        for (int j = 0; j < 4; ++j) acc[i][j] = (floatx4){0.f, 0.f, 0.f, 0.f};

    const int dpo = (tid & 15) * 8;
    const int rsel = tid >> 4;
    const int wsw = ((tid & 15) & 3) << 3;
    for (int k0 = 0; k0 < 128; k0 += 32) {
        __syncthreads();
        #pragma unroll
        for (int s = 0; s < 2; ++s) {   // coalesced: 16 lanes read one row's 256B chunk
            const int i = k0 + s * 16 + rsel;
            const half8 v = *(const half8*)(Hh + (size_t)(i * 128 + jc) * DIM + d0 + dpo);
            #pragma unroll
            for (int u = 0; u < 8; ++u)
                Bs[(dpo + u) * BP + ((s * 16 + rsel) ^ wsw)] = v[u];
        }
        __syncthreads();
        half8 af[4], bf[4];
        #pragma unroll
        for (int i = 0; i < 4; ++i)
            af[i] = *(const half8*)(Es + (mrow + i * 16 + l15) * EP + k0 + q * 8);
        #pragma unroll
        for (int j = 0; j < 4; ++j) {
            const int row = ncol + j * 16 + l15;
            bf[j] = *(const half8*)(Bs + row * BP + ((q ^ ((row >> 3) & 3)) << 3));
        }
        #pragma unroll
        for (int i = 0; i < 4; ++i)
            #pragma unroll
            for (int j = 0; j < 4; ++j)
                acc[i][j] = __builtin_amdgcn_mfma_f32_16x16x32_f16(af[i], bf[j], acc[i][j], 0, 0, 0);
    }
    __syncthreads();
    // fused epilogue: fp32 bounce in 2 chunks of 64 rows (m = ic)
    float* Ebf = (float*)Es;            // [64][132] floats
    #pragma unroll
    for (int ch = 0; ch < 2; ++ch) {
        if ((wv >> 1) == ch) {
            #pragma unroll
            for (int i = 0; i < 4; ++i)
                #pragma unroll
                for (int j = 0; j < 4; ++j)
                    #pragma unroll
                    for (int r = 0; r < 4; ++r)
                        Ebf[(i * 16 + q * 4 + r) * 132 + ncol + j * 16 + l15] = acc[i][j][r];
        }
        __syncthreads();
        {
            const int row = tid >> 2, seg = tid & 3;    // 64 rows x 4 segs of 32 floats
            const int m = ch * 64 + row;                // ic
            const int c = m * 128 + jc;
            const float scl = 1.f - alpha * Ss[m];
            const size_t g = (size_t)c * DIM + d0 + seg * 32;
            #pragma unroll
            for (int u = 0; u < 8; ++u) {
                float4 wv4 = *(const float4*)(w + g + u * 4);
                float4 t4  = *(const float4*)(Ebf + row * 132 + seg * 32 + u * 4);
                float4 o;
                o.x = wv4.x * scl + alpha * t4.x;
                o.y = wv4.y * scl + alpha * t4.y;
                o.z = wv4.z * scl + alpha * t4.z;
                o.w = wv4.w * scl + alpha * t4.w;
                *(float4*)(out + g + u * 4) = o;
            }
        }
        __syncthreads();
    }
}

extern "C" void kernel_launch(void* const* d_in, const int* in_sizes, int n_in,
                              void* d_out, int out_size, void* d_ws, size_t ws_size,
                              hipStream_t stream) {
    const float* x  = (const float*)d_in[0];   // [4096, 768]
    const float* w  = (const float*)d_in[1];   // [16384, 768]
    const int* itp  = (const int*)d_in[2];     // scalar it
    float* out = (float*)d_out;                // [16384, 768]
    char* ws = (char*)d_ws;

    _Float16* xh = (_Float16*)(ws + XH_OFF);
    _Float16* wh = (_Float16*)(ws + WH_OFF);
    _Float16* Gh = (_Float16*)(ws + G_OFF);    // fp16 G, aliases xh/wh post-bmu
    unsigned long long* best = (unsigned long long*)(ws + BEST_OFF);
    float* cnt  = (float*)(ws + CNT_OFF);
    float* wn2  = (float*)(ws + WN2_OFF);

    hipMemsetAsync(ws + BEST_OFF, 0, BEST_BYTES + CNT_BYTES, stream);

    cvt_kernel<<<(BS * DIM / 4 + 255) / 256, 256, 0, stream>>>(x, xh, BS * DIM / 4);
    cvtw_wn2_kernel<<<COMPS, 192, 0, stream>>>(w, wh, wn2);

    // 1024 blocks = 16 b-tiles x 64 c-tiles (XCD-remapped inside the kernel)
    bmu_kernel<<<dim3(1024), 512, 0, stream>>>(xh, wh, wn2, best);

    // xh/wh dead -> zero fp16 G (stream-ordered after bmu)
    hipMemsetAsync(ws + G_OFF, 0, GH_BYTES, stream);
    scatter_kernel<<<BS, 192, 0, stream>>>(best, x, Gh, cnt);

    // pass A: conv along j, H fp16 written in-place over G
    convA_kernel<<<dim3(6, 128), 256, 0, stream>>>(Gh, Gh, itp);
    // pass B + count-conv + epilogue -> d_out
    convB_kernel<<<dim3(6, 128), 256, 0, stream>>>(Gh, w, cnt, itp, out);
}

// Round 14
// 315.069 us; speedup vs baseline: 6.4914x; 1.0017x over previous
//
#include <hip/hip_runtime.h>
#include <hip/hip_fp16.h>
#include <cstdint>
#include <cstddef>

// ---------------- problem constants ----------------
#define BS    4096
#define DIM   768
#define GM    128
#define GN    128
#define COMPS (GM * GN)          // 16384
#define NITER_F 1000.0f
#define ALPHA0  0.3f
#define SIGMA0  64.0f            // max(M,N)/2

typedef _Float16 half8  __attribute__((ext_vector_type(8)));
typedef _Float16 half4v __attribute__((ext_vector_type(4)));
typedef _Float16 half2v __attribute__((ext_vector_type(2)));
typedef float    floatx4 __attribute__((ext_vector_type(4)));

// ---------------- workspace layout (bytes) ----------------
// Phase 1 (pre-bmu): xh fp16 @0 (6.3MB), wh fp16 @8MB (25.2MB).
// Phase 2 (post-bmu): G fp16 @0 (25.2MB) — aliases xh + wh[0..17MB], both
// dead after bmu. Scatter reads the ORIGINAL fp32 x (xh is zeroed by memset).
// H fp16 written IN-PLACE over G by convA (block reads = block writes range).
// Tails (best/cnt/wn2) at legacy >50.33MB offsets (above wh's end).
#define XH_OFF    0UL
#define WH_OFF    (8UL * 1024UL * 1024UL)
#define G_OFF     0UL
#define GH_BYTES  ((size_t)COMPS * DIM * 2UL)     // 25,165,824 (fp16 G/H)
#define BEST_OFF  ((size_t)COMPS * DIM * 4UL)     // 50,331,648 (legacy offset, > wh end)
#define BEST_BYTES ((size_t)BS * 8UL)             // 32 KB
#define CNT_OFF   (BEST_OFF + BEST_BYTES)
#define CNT_BYTES ((size_t)COMPS * 4UL)           // 64 KB
#define WN2_OFF   (CNT_OFF + CNT_BYTES)

#define GPTR(p) ((const __attribute__((address_space(1))) void*)(p))
#define LPTR(p) ((__attribute__((address_space(3))) void*)(p))

// pack (score, index) so that u64 max == (max score, min index on ties)
__device__ __forceinline__ unsigned long long packScore(float s, int c) {
    unsigned u = __float_as_uint(s);
    u = (u & 0x80000000u) ? ~u : (u | 0x80000000u);   // order-preserving map
    return ((unsigned long long)u << 32) | (unsigned)(~(unsigned)c);
}

__device__ __forceinline__ unsigned long long shfl_xor_u64(unsigned long long v, int m) {
    unsigned lo = (unsigned)v, hi = (unsigned)(v >> 32);
    lo = (unsigned)__shfl_xor((int)lo, m, 64);
    hi = (unsigned)__shfl_xor((int)hi, m, 64);
    return ((unsigned long long)hi << 32) | lo;
}

// packed fp16 atomic add — ROCm headers lack the __half2 atomicAdd overload;
// emit the gfx950 instruction directly (no return value needed).
__device__ __forceinline__ void atomicAddPkF16(_Float16* p, half2v v) {
    asm volatile("global_atomic_pk_add_f16 %0, %1, off" : : "v"(p), "v"(v) : "memory");
}

// ---------------- fp32 -> fp16 convert (x) ----------------
__global__ void cvt_kernel(const float* __restrict__ src, _Float16* __restrict__ dst, int n4) {
    int i = blockIdx.x * 256 + threadIdx.x;
    if (i >= n4) return;
    float4 v = ((const float4*)src)[i];
    half4v h;
    h[0] = (_Float16)v.x; h[1] = (_Float16)v.y;
    h[2] = (_Float16)v.z; h[3] = (_Float16)v.w;
    ((half4v*)dst)[i] = h;
}

// ---------------- w: fp32->fp16 convert fused with 0.5*||w_c||^2 ----------------
__global__ __launch_bounds__(192) void cvtw_wn2_kernel(
    const float* __restrict__ w, _Float16* __restrict__ wh, float* __restrict__ wn2) {
    const int c = blockIdx.x;
    const int t = threadIdx.x;                   // 0..191 (one float4 each)
    const size_t i4 = (size_t)c * 192 + t;
    float4 v = ((const float4*)w)[i4];
    half4v h;
    h[0] = (_Float16)v.x; h[1] = (_Float16)v.y;
    h[2] = (_Float16)v.z; h[3] = (_Float16)v.w;
    ((half4v*)wh)[i4] = h;
    float s = v.x * v.x + v.y * v.y + v.z * v.z + v.w * v.w;
    #pragma unroll
    for (int off = 32; off; off >>= 1) s += __shfl_down(s, off, 64);
    __shared__ float p[3];
    if ((t & 63) == 0) p[t >> 6] = s;
    __syncthreads();
    if (t == 0) wn2[c] = 0.5f * (p[0] + p[1] + p[2]);
}

// ---------------- MFMA BMU v7: BK=64, 12 barriers (was 24), 2-deep ring ----
// best_b = argmax_c (x_b.w_c - 0.5||w_c||^2).
// 256x256 tile, 8 waves (2M x 4N), per-wave 128x64, 16x16x32 MFMA, acc[8][4].
// v7 vs v6: BK 32->64. Same LDS (2 bufs x (A 32KB + B 32KB) = 128KB), same
// MFMA/ds_read/stage totals, HALF the barrier+drain sequences. Depth-1
// prefetch + vmcnt(0): stage(t+1) issues early in iter t, has a full
// ~7000-cycle iteration to land (HBM ~900cy) -> drain is free.
// Ring race: stage(t+1)->buf[(t+1)&1]; its last reads (iter t-1) retired
// before top-of-t barrier (consumed by MFMAs); stage issues after. Safe.
// LDS layout: row = line (64 halves = 128B/row), phys slot = ck ^ (row&7),
// ck = h*4+q. Per 8-consecutive-lane HW phase group, ps is a permutation of
// 0..7 -> conflict-free (v5's 32x32 failure was lanes-per-group aliasing,
// not present here). K-order bit-identical to v6 (t*64+[0,32) then [32,64)).
// Session ledger (do not re-try): v3 phase-split barrier pairs (regressed);
// v4 launch_bounds(512,4) (spill); v5 32x32x16 (structural 4-way conflict).
#define BMU_NT 12   // 768 / 64

__global__ __launch_bounds__(512, 2) void bmu_kernel(
    const _Float16* __restrict__ xh, const _Float16* __restrict__ wh,
    const float* __restrict__ wn2, unsigned long long* __restrict__ best) {
    __shared__ _Float16 AB[2][2][16384];      // [buf][A,B][256 rows x 64 halves] = 128KB
    __shared__ unsigned long long red[256];

    const int tid  = threadIdx.x;
    const int wv   = tid >> 6;
    const int lane = tid & 63;
    const int l15  = lane & 15;
    const int q    = lane >> 4;
    const int wr   = wv >> 2;        // 0..1 (M half)
    const int wc   = wv & 3;         // 0..3 (N quarter)

    // XCD-aware remap (measured FETCH 110->71MB): each XCD owns 8 w-tiles;
    // concurrent window = 4 w-tiles x 8 x-tiles = 4.7MB vs 4MB L2.
    const int bid = blockIdx.x;      // 0..1023
    const int xcd = bid & 7;
    const int rem = bid >> 3;        // 0..127
    const int cbl = rem & 3;         // w tile (inner, 4 concurrent)
    const int bb  = (rem >> 2) & 15; // x tile (middle)
    const int cbg = rem >> 6;        // 0..1 (outer w group)
    const int cb  = xcd * 8 + cbg * 4 + cbl;
    const int b0 = bb * 256;
    const int c0 = cb * 256;

    if (tid < 256) red[tid] = 0ULL;

    // staging decomposition: round ra covers rows [64ra, 64ra+64);
    // 512 threads x 16B = 8KB per round; 4 rounds per matrix per K-tile.
    // Pre-swizzled source: thread (rowi, ss) loads logical chunk sl = ss^(rowi&7)
    // so the linear LDS dest (phys slot ss) holds logical (ss^(row&7)).
    const int rowi = tid >> 3;       // 0..63 row within round
    const int ss   = tid & 7;        // phys slot == linear dest slot
    const int sl   = ss ^ (rowi & 7);
    const _Float16* gA0 = xh + (size_t)(b0 +   0 + rowi) * DIM + sl * 8;
    const _Float16* gA1 = xh + (size_t)(b0 +  64 + rowi) * DIM + sl * 8;
    const _Float16* gA2 = xh + (size_t)(b0 + 128 + rowi) * DIM + sl * 8;
    const _Float16* gA3 = xh + (size_t)(b0 + 192 + rowi) * DIM + sl * 8;
    const _Float16* gB0 = wh + (size_t)(c0 +   0 + rowi) * DIM + sl * 8;
    const _Float16* gB1 = wh + (size_t)(c0 +  64 + rowi) * DIM + sl * 8;
    const _Float16* gB2 = wh + (size_t)(c0 + 128 + rowi) * DIM + sl * 8;
    const _Float16* gB3 = wh + (size_t)(c0 + 192 + rowi) * DIM + sl * 8;
    const int ldsoff = wv * 512;     // halves: wave-uniform base within a round

    // fragment LDS offsets (halves), h=0 (ck=q); h=1 (ck=4+q) = ^32
    int aoff[8], boff[4];
    #pragma unroll
    for (int i = 0; i < 8; ++i) {
        const int row = wr * 128 + i * 16 + l15;
        aoff[i] = row * 64 + (q ^ (row & 7)) * 8;
    }
    #pragma unroll
    for (int jj = 0; jj < 4; ++jj) {
        const int row = wc * 64 + jj * 16 + l15;
        boff[jj] = row * 64 + (q ^ (row & 7)) * 8;
    }

    floatx4 acc[8][4];
    #pragma unroll
    for (int i = 0; i < 8; ++i)
        #pragma unroll
        for (int jj = 0; jj < 4; ++jj) acc[i][jj] = (floatx4){0.f, 0.f, 0.f, 0.f};

    // prologue: stage tile 0 (8 loads)
    {
        _Float16* A = &AB[0][0][0];
        _Float16* B = &AB[0][1][0];
        __builtin_amdgcn_global_load_lds(GPTR(gA0), LPTR(A +     0 + ldsoff), 16, 0, 0);
        __builtin_amdgcn_global_load_lds(GPTR(gA1), LPTR(A +  4096 + ldsoff), 16, 0, 0);
        __builtin_amdgcn_global_load_lds(GPTR(gA2), LPTR(A +  8192 + ldsoff), 16, 0, 0);
        __builtin_amdgcn_global_load_lds(GPTR(gA3), LPTR(A + 12288 + ldsoff), 16, 0, 0);
        __builtin_amdgcn_global_load_lds(GPTR(gB0), LPTR(B +     0 + ldsoff), 16, 0, 0);
        __builtin_amdgcn_global_load_lds(GPTR(gB1), LPTR(B +  4096 + ldsoff), 16, 0, 0);
        __builtin_amdgcn_global_load_lds(GPTR(gB2), LPTR(B +  8192 + ldsoff), 16, 0, 0);
        __builtin_amdgcn_global_load_lds(GPTR(gB3), LPTR(B + 12288 + ldsoff), 16, 0, 0);
    }

    for (int t = 0; t < BMU_NT; ++t) {
        // drain stage(t) (issued a full iteration ago), publish tile t
        asm volatile("s_waitcnt vmcnt(0)" ::: "memory");
        __builtin_amdgcn_s_barrier();
        asm volatile("" ::: "memory");   // no LDS-read hoisting above the barrier

        const _Float16* A = &AB[t & 1][0][0];
        const _Float16* B = &AB[t & 1][1][0];
        const bool more = (t + 1) < BMU_NT;
        _Float16* An = &AB[(t + 1) & 1][0][0];
        _Float16* Bn = &AB[(t + 1) & 1][1][0];
        const int tk = (t + 1) * 64;

        half8 af[8], bf[4];
        // ======== k-half h=0 (ck = q) ========
        #pragma unroll
        for (int i = 0; i < 4; ++i) af[i] = *(const half8*)(A + aoff[i]);
        bf[0] = *(const half8*)(B + boff[0]);
        bf[1] = *(const half8*)(B + boff[1]);
        if (more) __builtin_amdgcn_global_load_lds(GPTR(gA0 + tk), LPTR(An + 0 + ldsoff), 16, 0, 0);
        __builtin_amdgcn_s_setprio(1);
        #pragma unroll
        for (int i = 0; i < 4; ++i) {
            acc[i][0] = __builtin_amdgcn_mfma_f32_16x16x32_f16(af[i], bf[0], acc[i][0], 0, 0, 0);
            acc[i][1] = __builtin_amdgcn_mfma_f32_16x16x32_f16(af[i], bf[1], acc[i][1], 0, 0, 0);
        }
        __builtin_amdgcn_s_setprio(0);
        #pragma unroll
        for (int i = 4; i < 8; ++i) af[i] = *(const half8*)(A + aoff[i]);
        if (more) __builtin_amdgcn_global_load_lds(GPTR(gA1 + tk), LPTR(An + 4096 + ldsoff), 16, 0, 0);
        __builtin_amdgcn_s_setprio(1);
        #pragma unroll
        for (int i = 4; i < 8; ++i) {
            acc[i][0] = __builtin_amdgcn_mfma_f32_16x16x32_f16(af[i], bf[0], acc[i][0], 0, 0, 0);
            acc[i][1] = __builtin_amdgcn_mfma_f32_16x16x32_f16(af[i], bf[1], acc[i][1], 0, 0, 0);
        }
        __builtin_amdgcn_s_setprio(0);
        bf[2] = *(const half8*)(B + boff[2]);
        bf[3] = *(const half8*)(B + boff[3]);
        if (more) __builtin_amdgcn_global_load_lds(GPTR(gA2 + tk), LPTR(An + 8192 + ldsoff), 16, 0, 0);
        __builtin_amdgcn_s_setprio(1);
        #pragma unroll
        for (int i = 4; i < 8; ++i) {
            acc[i][2] = __builtin_amdgcn_mfma_f32_16x16x32_f16(af[i], bf[2], acc[i][2], 0, 0, 0);
            acc[i][3] = __builtin_amdgcn_mfma_f32_16x16x32_f16(af[i], bf[3], acc[i][3], 0, 0, 0);
        }
        __builtin_amdgcn_s_setprio(0);
        if (more) __builtin_amdgcn_global_load_lds(GPTR(gA3 + tk), LPTR(An + 12288 + ldsoff), 16, 0, 0);
        __builtin_amdgcn_s_setprio(1);
        #pragma unroll
        for (int i = 0; i < 4; ++i) {
            acc[i][2] = __builtin_amdgcn_mfma_f32_16x16x32_f16(af[i], bf[2], acc[i][2], 0, 0, 0);
            acc[i][3] = __builtin_amdgcn_mfma_f32_16x16x32_f16(af[i], bf[3], acc[i][3], 0, 0, 0);
        }
        __builtin_amdgcn_s_setprio(0);
        // ======== k-half h=1 (ck = 4+q; offset ^32) ========
        #pragma unroll
        for (int i = 0; i < 4; ++i) af[i] = *(const half8*)(A + (aoff[i] ^ 32));
        bf[0] = *(const half8*)(B + (boff[0] ^ 32));
        bf[1] = *(const half8*)(B + (boff[1] ^ 32));
        if (more) __builtin_amdgcn_global_load_lds(GPTR(gB0 + tk), LPTR(Bn + 0 + ldsoff), 16, 0, 0);
        __builtin_amdgcn_s_setprio(1);
        #pragma unroll
        for (int i = 0; i < 4; ++i) {
            acc[i][0] = __builtin_amdgcn_mfma_f32_16x16x32_f16(af[i], bf[0], acc[i][0], 0, 0, 0);
            acc[i][1] = __builtin_amdgcn_mfma_f32_16x16x32_f16(af[i], bf[1], acc[i][1], 0, 0, 0);
        }
        __builtin_amdgcn_s_setprio(0);
        #pragma unroll
        for (int i = 4; i < 8; ++i) af[i] = *(const half8*)(A + (aoff[i] ^ 32));
        if (more) __builtin_amdgcn_global_load_lds(GPTR(gB1 + tk), LPTR(Bn + 4096 + ldsoff), 16, 0, 0);
        __builtin_amdgcn_s_setprio(1);
        #pragma unroll
        for (int i = 4; i < 8; ++i) {
            acc[i][0] = __builtin_amdgcn_mfma_f32_16x16x32_f16(af[i], bf[0], acc[i][0], 0, 0, 0);
            acc[i][1] = __builtin_amdgcn_mfma_f32_16x16x32_f16(af[i], bf[1], acc[i][1], 0, 0, 0);
        }
        __builtin_amdgcn_s_setprio(0);
        bf[2] = *(const half8*)(B + (boff[2] ^ 32));
        bf[3] = *(const half8*)(B + (boff[3] ^ 32));
        if (more) __builtin_amdgcn_global_load_lds(GPTR(gB2 + tk), LPTR(Bn + 8192 + ldsoff), 16, 0, 0);
        __builtin_amdgcn_s_setprio(1);
        #pragma unroll
        for (int i = 4; i < 8; ++i) {
            acc[i][2] = __builtin_amdgcn_mfma_f32_16x16x32_f16(af[i], bf[2], acc[i][2], 0, 0, 0);
            acc[i][3] = __builtin_amdgcn_mfma_f32_16x16x32_f16(af[i], bf[3], acc[i][3], 0, 0, 0);
        }
        __builtin_amdgcn_s_setprio(0);
        if (more) __builtin_amdgcn_global_load_lds(GPTR(gB3 + tk), LPTR(Bn + 12288 + ldsoff), 16, 0, 0);
        __builtin_amdgcn_s_setprio(1);
        #pragma unroll
        for (int i = 0; i < 4; ++i) {
            acc[i][2] = __builtin_amdgcn_mfma_f32_16x16x32_f16(af[i], bf[2], acc[i][2], 0, 0, 0);
            acc[i][3] = __builtin_amdgcn_mfma_f32_16x16x32_f16(af[i], bf[3], acc[i][3], 0, 0, 0);
        }
        __builtin_amdgcn_s_setprio(0);
    }

    // ---------------- argmax epilogue (unchanged) ----------------
    float wnj[4];
    #pragma unroll
    for (int jj = 0; jj < 4; ++jj) wnj[jj] = wn2[c0 + wc * 64 + jj * 16 + l15];

    #pragma unroll
    for (int i = 0; i < 8; ++i) {
        #pragma unroll
        for (int r = 0; r < 4; ++r) {
            unsigned long long m = 0ULL;
            #pragma unroll
            for (int jj = 0; jj < 4; ++jj) {
                const float s = acc[i][jj][r] - wnj[jj];
                const unsigned long long p = packScore(s, c0 + wc * 64 + jj * 16 + l15);
                if (p > m) m = p;
            }
            #pragma unroll
            for (int msk = 1; msk <= 8; msk <<= 1) {
                const unsigned long long o = shfl_xor_u64(m, msk);
                if (o > m) m = o;
            }
            if (l15 == 0)
                atomicMax(&red[wr * 128 + i * 16 + q * 4 + r], m);
        }
    }
    __syncthreads();
    if (tid < 256) atomicMax(&best[b0 + tid], red[tid]);
}

// ---------------- scatter x rows into fp16 G (packed half2 atomics) + histogram ----------------
// Reads the ORIGINAL fp32 x (not xh: xh is inside G's footprint and zeroed).
__global__ void scatter_kernel(const unsigned long long* __restrict__ best,
                               const float* __restrict__ x,
                               _Float16* __restrict__ Gh, float* __restrict__ cnt) {
    const int b = blockIdx.x;
    const int c = (int)(~(unsigned)(best[b] & 0xFFFFFFFFULL));
    _Float16* gr = Gh + (size_t)c * DIM;
    const float2* xr = (const float2*)(x + (size_t)b * DIM);
    #pragma unroll
    for (int u = 0; u < 2; ++u) {
        const int d = threadIdx.x + u * 192;   // 384 half2 = 768 halves
        const float2 v = xr[d];
        half2v h;
        h[0] = (_Float16)v.x; h[1] = (_Float16)v.y;
        atomicAddPkF16(gr + d * 2, h);         // global_atomic_pk_add_f16
    }
    if (threadIdx.x == 0) atomicAdd(&cnt[c], 1.0f);
}

#define EP 136   // Es pitch (halves)
#define BP 40    // Bs pitch (halves)
// Bs write conflict fix: writes put rows d=8k+u at a fixed col -> bank
// (20u + col/2) is k-independent = 16-way conflict; octet-preserving col
// swizzle: store col' = col ^ ((k&3)<<3) -> 4-way writes; reads use
// q' = q ^ ((row>>3)&3), still exactly 2 lanes/bank (free).

// ---- conv pass A (MFMA): H[(i,jc), d] = sum_j E[jc,j] * G[(i,j), d]; fp16 G, H in-place ----
__global__ __launch_bounds__(256) void convA_kernel(
    const _Float16* Gh, _Float16* Hh, const int* __restrict__ itp) {
    __shared__ _Float16 Es[128 * EP];   // E fp16, later reused as fp32 bounce
    __shared__ _Float16 Bs[128 * BP];
    const int d0 = blockIdx.x * 128;    // 0..5
    const int ib = blockIdx.y;          // 0..127
    const int tid = threadIdx.x;
    const int wv = tid >> 6, lane = tid & 63;
    const int l15 = lane & 15, q = lane >> 4;
    const int mrow = (wv >> 1) * 64, ncol = (wv & 1) * 64;

    {   // compute E tile in LDS on the fly
        const float decay = 1.f - (float)(*itp) / NITER_F;
        const float sig = SIGMA0 * decay;
        const float inv = -1.f / (sig * sig);
        const int row = tid >> 1, hh = tid & 1;
        _Float16* dst = Es + row * EP + hh * 64;
        #pragma unroll
        for (int u = 0; u < 64; ++u) {
            const float dd = (float)(row - hh * 64 - u);
            dst[u] = (_Float16)__expf(dd * dd * inv);
        }
    }

    floatx4 acc[4][4];
    #pragma unroll
    for (int i = 0; i < 4; ++i)
        #pragma unroll
        for (int j = 0; j < 4; ++j) acc[i][j] = (floatx4){0.f, 0.f, 0.f, 0.f};

    const int dpo = (tid & 15) * 8;     // d-octet within 128
    const int rsel = tid >> 4;          // 0..15 row selector
    const int wsw = ((tid & 15) & 3) << 3;   // write col-swizzle = (k&3)<<3
    for (int k0 = 0; k0 < 128; k0 += 32) {
        __syncthreads();
        #pragma unroll
        for (int s = 0; s < 2; ++s) {   // coalesced: 16 lanes read one row's 256B
            const int j = k0 + s * 16 + rsel;
            const half8 v = *(const half8*)(Gh + (size_t)(ib * 128 + j) * DIM + d0 + dpo);
            #pragma unroll
            for (int u = 0; u < 8; ++u)
                Bs[(dpo + u) * BP + ((s * 16 + rsel) ^ wsw)] = v[u];
        }
        __syncthreads();
        half8 af[4], bf[4];
        #pragma unroll
        for (int i = 0; i < 4; ++i)
            af[i] = *(const half8*)(Es + (mrow + i * 16 + l15) * EP + k0 + q * 8);
        #pragma unroll
        for (int j = 0; j < 4; ++j) {
            const int row = ncol + j * 16 + l15;
            bf[j] = *(const half8*)(Bs + row * BP + ((q ^ ((row >> 3) & 3)) << 3));
        }
        #pragma unroll
        for (int i = 0; i < 4; ++i)
            #pragma unroll
            for (int j = 0; j < 4; ++j)
                acc[i][j] = __builtin_amdgcn_mfma_f32_16x16x32_f16(af[i], bf[j], acc[i][j], 0, 0, 0);
    }
    __syncthreads();
    // fp32 bounce epilogue in 2 chunks of 64 rows (m = jc); H fp16 natural
    // layout, in-place over G (this block's exact read range, reads done).
    float* Ebf = (float*)Es;            // [64][132] floats = 33792 B <= 34816
    #pragma unroll
    for (int ch = 0; ch < 2; ++ch) {
        if ((wv >> 1) == ch) {
            #pragma unroll
            for (int i = 0; i < 4; ++i)
                #pragma unroll
                for (int j = 0; j < 4; ++j)
                    #pragma unroll
                    for (int r = 0; r < 4; ++r)
                        Ebf[(i * 16 + q * 4 + r) * 132 + ncol + j * 16 + l15] = acc[i][j][r];
        }
        __syncthreads();
        {
            const int row = tid >> 2, seg = tid & 3;    // 64 rows x 4 segs of 32
            const int m = ch * 64 + row;                // jc
            _Float16* hp = Hh + (size_t)(ib * 128 + m) * DIM + d0 + seg * 32;
            #pragma unroll
            for (int u = 0; u < 4; ++u) {
                const float* sp = Ebf + row * 132 + seg * 32 + u * 8;
                half8 hv;
                #pragma unroll
                for (int e = 0; e < 8; ++e) hv[e] = (_Float16)sp[e];
                *(half8*)(hp + u * 8) = hv;
            }
        }
        __syncthreads();
    }
}

// ---- conv pass B (MFMA) + fused S-conv + epilogue:
//      out[(ic,jc),d] = w*(1-a*S[ic,jc]) + a * sum_i E[ic,i] H[(i,jc),d]
__global__ __launch_bounds__(256) void convB_kernel(
    const _Float16* Hh, const float* __restrict__ w, const float* __restrict__ cnt,
    const int* __restrict__ itp, float* __restrict__ out) {
    __shared__ _Float16 Es[128 * EP];
    __shared__ _Float16 Bs[128 * BP];
    __shared__ float cntHs[128];
    __shared__ float Ss[128];
    const int d0 = blockIdx.x * 128;    // 0..5
    const int jc = blockIdx.y;          // 0..127
    const int tid = threadIdx.x;
    const int wv = tid >> 6, lane = tid & 63;
    const int l15 = lane & 15, q = lane >> 4;
    const int mrow = (wv >> 1) * 64, ncol = (wv & 1) * 64;
    const float decay = 1.f - (float)(*itp) / NITER_F;
    const float alpha = ALPHA0 * decay;
    const float sig = SIGMA0 * decay;
    const float inv = -1.f / (sig * sig);

    // count-conv for this jc column (S[ic] for all ic), fp32
    if (tid < 128) {
        float s = 0.f;
        for (int j = 0; j < 128; ++j) {
            const float dd = (float)(jc - j);
            s += __expf(dd * dd * inv) * cnt[tid * 128 + j];
        }
        cntHs[tid] = s;
    }
    {   // compute E tile in LDS
        const int row = tid >> 1, hh = tid & 1;
        _Float16* dst = Es + row * EP + hh * 64;
        #pragma unroll
        for (int u = 0; u < 64; ++u) {
            const float dd = (float)(row - hh * 64 - u);
            dst[u] = (_Float16)__expf(dd * dd * inv);
        }
    }
    __syncthreads();
    if (tid < 128) {
        float s = 0.f;
        for (int i = 0; i < 128; ++i) {
            const float dd = (float)(tid - i);
            s += __expf(dd * dd * inv) * cntHs[i];
        }
        Ss[tid] = s;
    }

    floatx4 acc[4][4];
    #pragma unroll
    for (int i = 0; i < 4; ++i)
        #pragma unroll
        for (int j = 0; j < 4; ++j) acc[i][j] = (floatx4){0.f, 0.f, 0.f, 0.f};

    const int dpo = (tid & 15) * 8;
    const int rsel = tid >> 4;
    const int wsw = ((tid & 15) & 3) << 3;
    for (int k0 = 0; k0 < 128; k0 += 32) {
        __syncthreads();
        #pragma unroll
        for (int s = 0; s < 2; ++s) {   // coalesced: 16 lanes read one row's 256B chunk
            const int i = k0 + s * 16 + rsel;
            const half8 v = *(const half8*)(Hh + (size_t)(i * 128 + jc) * DIM + d0 + dpo);
            #pragma unroll
            for (int u = 0; u < 8; ++u)
                Bs[(dpo + u) * BP + ((s * 16 + rsel) ^ wsw)] = v[u];
        }
        __syncthreads();
        half8 af[4], bf[4];
        #pragma unroll
        for (int i = 0; i < 4; ++i)
            af[i] = *(const half8*)(Es + (mrow + i * 16 + l15) * EP + k0 + q * 8);
        #pragma unroll
        for (int j = 0; j < 4; ++j) {
            const int row = ncol + j * 16 + l15;
            bf[j] = *(const half8*)(Bs + row * BP + ((q ^ ((row >> 3) & 3)) << 3));
        }
        #pragma unroll
        for (int i = 0; i < 4; ++i)
            #pragma unroll
            for (int j = 0; j < 4; ++j)
                acc[i][j] = __builtin_amdgcn_mfma_f32_16x16x32_f16(af[i], bf[j], acc[i][j], 0, 0, 0);
    }
    __syncthreads();
    // fused epilogue: fp32 bounce in 2 chunks of 64 rows (m = ic)
    float* Ebf = (float*)Es;            // [64][132] floats
    #pragma unroll
    for (int ch = 0; ch < 2; ++ch) {
        if ((wv >> 1) == ch) {
            #pragma unroll
            for (int i = 0; i < 4; ++i)
                #pragma unroll
                for (int j = 0; j < 4; ++j)
                    #pragma unroll
                    for (int r = 0; r < 4; ++r)
                        Ebf[(i * 16 + q * 4 + r) * 132 + ncol + j * 16 + l15] = acc[i][j][r];
        }
        __syncthreads();
        {
            const int row = tid >> 2, seg = tid & 3;    // 64 rows x 4 segs of 32 floats
            const int m = ch * 64 + row;                // ic
            const int c = m * 128 + jc;
            const float scl = 1.f - alpha * Ss[m];
            const size_t g = (size_t)c * DIM + d0 + seg * 32;
            #pragma unroll
            for (int u = 0; u < 8; ++u) {
                float4 wv4 = *(const float4*)(w + g + u * 4);
                float4 t4  = *(const float4*)(Ebf + row * 132 + seg * 32 + u * 4);
                float4 o;
                o.x = wv4.x * scl + alpha * t4.x;
                o.y = wv4.y * scl + alpha * t4.y;
                o.z = wv4.z * scl + alpha * t4.z;
                o.w = wv4.w * scl + alpha * t4.w;
                *(float4*)(out + g + u * 4) = o;
            }
        }
        __syncthreads();
    }
}

extern "C" void kernel_launch(void* const* d_in, const int* in_sizes, int n_in,
                              void* d_out, int out_size, void* d_ws, size_t ws_size,
                              hipStream_t stream) {
    const float* x  = (const float*)d_in[0];   // [4096, 768]
    const float* w  = (const float*)d_in[1];   // [16384, 768]
    const int* itp  = (const int*)d_in[2];     // scalar it
    float* out = (float*)d_out;                // [16384, 768]
    char* ws = (char*)d_ws;

    _Float16* xh = (_Float16*)(ws + XH_OFF);
    _Float16* wh = (_Float16*)(ws + WH_OFF);
    _Float16* Gh = (_Float16*)(ws + G_OFF);    // fp16 G, aliases xh/wh post-bmu
    unsigned long long* best = (unsigned long long*)(ws + BEST_OFF);
    float* cnt  = (float*)(ws + CNT_OFF);
    float* wn2  = (float*)(ws + WN2_OFF);

    hipMemsetAsync(ws + BEST_OFF, 0, BEST_BYTES + CNT_BYTES, stream);

    cvt_kernel<<<(BS * DIM / 4 + 255) / 256, 256, 0, stream>>>(x, xh, BS * DIM / 4);
    cvtw_wn2_kernel<<<COMPS, 192, 0, stream>>>(w, wh, wn2);

    // 1024 blocks = 16 b-tiles x 64 c-tiles (XCD-remapped inside the kernel)
    bmu_kernel<<<dim3(1024), 512, 0, stream>>>(xh, wh, wn2, best);

    // xh/wh dead -> zero fp16 G (stream-ordered after bmu)
    hipMemsetAsync(ws + G_OFF, 0, GH_BYTES, stream);
    scatter_kernel<<<BS, 192, 0, stream>>>(best, x, Gh, cnt);

    // pass A: conv along j, H fp16 written in-place over G
    convA_kernel<<<dim3(6, 128), 256, 0, stream>>>(Gh, Gh, itp);
    // pass B + count-conv + epilogue -> d_out
    convB_kernel<<<dim3(6, 128), 256, 0, stream>>>(Gh, w, cnt, itp, out);
}

// Round 16
// 313.793 us; speedup vs baseline: 6.5178x; 1.0041x over previous
//
#include <hip/hip_runtime.h>
#include <hip/hip_fp16.h>
#include <cstdint>
#include <cstddef>

// ---------------- problem constants ----------------
#define BS    4096
#define DIM   768
#define GM    128
#define GN    128
#define COMPS (GM * GN)          // 16384
#define NITER_F 1000.0f
#define ALPHA0  0.3f
#define SIGMA0  64.0f            // max(M,N)/2

typedef _Float16 half8  __attribute__((ext_vector_type(8)));
typedef _Float16 half4v __attribute__((ext_vector_type(4)));
typedef _Float16 half2v __attribute__((ext_vector_type(2)));
typedef float    floatx4 __attribute__((ext_vector_type(4)));

// ---------------- workspace layout (bytes) ----------------
// Phase 1 (pre-bmu): xh fp16 @0 (6.3MB), wh fp16 @8MB (25.2MB).
// Phase 2 (post-bmu): G fp16 @0 (25.2MB) — aliases xh + wh[0..17MB], both
// dead after bmu. Scatter reads the ORIGINAL fp32 x (xh is zeroed by memset).
// H fp16 written IN-PLACE over G by convA (block reads = block writes range).
// Tails (best/cnt/wn2) at legacy >50.33MB offsets (above wh's end).
#define XH_OFF    0UL
#define WH_OFF    (8UL * 1024UL * 1024UL)
#define G_OFF     0UL
#define GH_BYTES  ((size_t)COMPS * DIM * 2UL)     // 25,165,824 (fp16 G/H)
#define BEST_OFF  ((size_t)COMPS * DIM * 4UL)     // 50,331,648 (legacy offset, > wh end)
#define BEST_BYTES ((size_t)BS * 8UL)             // 32 KB
#define CNT_OFF   (BEST_OFF + BEST_BYTES)
#define CNT_BYTES ((size_t)COMPS * 4UL)           // 64 KB
#define WN2_OFF   (CNT_OFF + CNT_BYTES)

#define GPTR(p) ((const __attribute__((address_space(1))) void*)(p))
#define LPTR(p) ((__attribute__((address_space(3))) void*)(p))

// pack (score, index) so that u64 max == (max score, min index on ties)
__device__ __forceinline__ unsigned long long packScore(float s, int c) {
    unsigned u = __float_as_uint(s);
    u = (u & 0x80000000u) ? ~u : (u | 0x80000000u);   // order-preserving map
    return ((unsigned long long)u << 32) | (unsigned)(~(unsigned)c);
}

__device__ __forceinline__ unsigned long long shfl_xor_u64(unsigned long long v, int m) {
    unsigned lo = (unsigned)v, hi = (unsigned)(v >> 32);
    lo = (unsigned)__shfl_xor((int)lo, m, 64);
    hi = (unsigned)__shfl_xor((int)hi, m, 64);
    return ((unsigned long long)hi << 32) | lo;
}

// packed fp16 atomic add — ROCm headers lack the __half2 atomicAdd overload;
// emit the gfx950 instruction directly (no return value needed).
__device__ __forceinline__ void atomicAddPkF16(_Float16* p, half2v v) {
    asm volatile("global_atomic_pk_add_f16 %0, %1, off" : : "v"(p), "v"(v) : "memory");
}

// ---------------- fp32 -> fp16 convert (x), fused with best/cnt zeroing ----------------
// Zeroing folded here (saves one hipMemsetAsync launch). Stream order
// guarantees: best zeroed before bmu (next-next launch), cnt before scatter.
__global__ void cvt_kernel(const float* __restrict__ src, _Float16* __restrict__ dst, int n4,
                           unsigned long long* __restrict__ best, float* __restrict__ cnt) {
    int i = blockIdx.x * 256 + threadIdx.x;
    if (i < BS) best[i] = 0ULL;
    if (i < COMPS) cnt[i] = 0.f;
    if (i >= n4) return;
    float4 v = ((const float4*)src)[i];
    half4v h;
    h[0] = (_Float16)v.x; h[1] = (_Float16)v.y;
    h[2] = (_Float16)v.z; h[3] = (_Float16)v.w;
    ((half4v*)dst)[i] = h;
}

// ---------------- w: fp32->fp16 convert fused with 0.5*||w_c||^2 ----------------
__global__ __launch_bounds__(192) void cvtw_wn2_kernel(
    const float* __restrict__ w, _Float16* __restrict__ wh, float* __restrict__ wn2) {
    const int c = blockIdx.x;
    const int t = threadIdx.x;                   // 0..191 (one float4 each)
    const size_t i4 = (size_t)c * 192 + t;
    float4 v = ((const float4*)w)[i4];
    half4v h;
    h[0] = (_Float16)v.x; h[1] = (_Float16)v.y;
    h[2] = (_Float16)v.z; h[3] = (_Float16)v.w;
    ((half4v*)wh)[i4] = h;
    float s = v.x * v.x + v.y * v.y + v.z * v.z + v.w * v.w;
    #pragma unroll
    for (int off = 32; off; off >>= 1) s += __shfl_down(s, off, 64);
    __shared__ float p[3];
    if ((t & 63) == 0) p[t >> 6] = s;
    __syncthreads();
    if (t == 0) wn2[c] = 0.5f * (p[0] + p[1] + p[2]);
}

// ---------------- MFMA BMU v7 (UNCHANGED, verified 136.8us / MfmaUtil 31 / 0 conflicts) ----
// BK=64, 12 barriers, 2-deep ring, depth-1 prefetch + vmcnt(0).
// Session ledger (do not re-try): v1 128²-high-occupancy (169us); v3
// phase-split barrier pairs (148); v4 launch_bounds(512,4) spill (1875);
// v5 32x32x16 structural 4-way conflict (185); BK=64 vs 32: -4us (kept).
// Cycle model: ~6850 cyc/CU/K-tile observed; MFMA pipe ~610, LDS reads
// ~2300 + staging writes ~500; rest = dependency stalls at 2 waves/SIMD.
#define BMU_NT 12   // 768 / 64

__global__ __launch_bounds__(512, 2) void bmu_kernel(
    const _Float16* __restrict__ xh, const _Float16* __restrict__ wh,
    const float* __restrict__ wn2, unsigned long long* __restrict__ best) {
    __shared__ _Float16 AB[2][2][16384];      // [buf][A,B][256 rows x 64 halves] = 128KB
    __shared__ unsigned long long red[256];

    const int tid  = threadIdx.x;
    const int wv   = tid >> 6;
    const int lane = tid & 63;
    const int l15  = lane & 15;
    const int q    = lane >> 4;
    const int wr   = wv >> 2;        // 0..1 (M half)
    const int wc   = wv & 3;         // 0..3 (N quarter)

    // XCD-aware remap (measured FETCH 110->71MB): each XCD owns 8 w-tiles;
    // concurrent window = 4 w-tiles x 8 x-tiles = 4.7MB vs 4MB L2.
    const int bid = blockIdx.x;      // 0..1023
    const int xcd = bid & 7;
    const int rem = bid >> 3;        // 0..127
    const int cbl = rem & 3;         // w tile (inner, 4 concurrent)
    const int bb  = (rem >> 2) & 15; // x tile (middle)
    const int cbg = rem >> 6;        // 0..1 (outer w group)
    const int cb  = xcd * 8 + cbg * 4 + cbl;
    const int b0 = bb * 256;
    const int c0 = cb * 256;

    if (tid < 256) red[tid] = 0ULL;

    // staging decomposition: round ra covers rows [64ra, 64ra+64);
    // pre-swizzled source: thread (rowi, ss) loads logical chunk sl = ss^(rowi&7)
    const int rowi = tid >> 3;       // 0..63 row within round
    const int ss   = tid & 7;        // phys slot == linear dest slot
    const int sl   = ss ^ (rowi & 7);
    const _Float16* gA0 = xh + (size_t)(b0 +   0 + rowi) * DIM + sl * 8;
    const _Float16* gA1 = xh + (size_t)(b0 +  64 + rowi) * DIM + sl * 8;
    const _Float16* gA2 = xh + (size_t)(b0 + 128 + rowi) * DIM + sl * 8;
    const _Float16* gA3 = xh + (size_t)(b0 + 192 + rowi) * DIM + sl * 8;
    const _Float16* gB0 = wh + (size_t)(c0 +   0 + rowi) * DIM + sl * 8;
    const _Float16* gB1 = wh + (size_t)(c0 +  64 + rowi) * DIM + sl * 8;
    const _Float16* gB2 = wh + (size_t)(c0 + 128 + rowi) * DIM + sl * 8;
    const _Float16* gB3 = wh + (size_t)(c0 + 192 + rowi) * DIM + sl * 8;
    const int ldsoff = wv * 512;     // halves: wave-uniform base within a round

    // fragment LDS offsets (halves), h=0 (ck=q); h=1 (ck=4+q) = ^32
    int aoff[8], boff[4];
    #pragma unroll
    for (int i = 0; i < 8; ++i) {
        const int row = wr * 128 + i * 16 + l15;
        aoff[i] = row * 64 + (q ^ (row & 7)) * 8;
    }
    #pragma unroll
    for (int jj = 0; jj < 4; ++jj) {
        const int row = wc * 64 + jj * 16 + l15;
        boff[jj] = row * 64 + (q ^ (row & 7)) * 8;
    }

    floatx4 acc[8][4];
    #pragma unroll
    for (int i = 0; i < 8; ++i)
        #pragma unroll
        for (int jj = 0; jj < 4; ++jj) acc[i][jj] = (floatx4){0.f, 0.f, 0.f, 0.f};

    // prologue: stage tile 0 (8 loads)
    {
        _Float16* A = &AB[0][0][0];
        _Float16* B = &AB[0][1][0];
        __builtin_amdgcn_global_load_lds(GPTR(gA0), LPTR(A +     0 + ldsoff), 16, 0, 0);
        __builtin_amdgcn_global_load_lds(GPTR(gA1), LPTR(A +  4096 + ldsoff), 16, 0, 0);
        __builtin_amdgcn_global_load_lds(GPTR(gA2), LPTR(A +  8192 + ldsoff), 16, 0, 0);
        __builtin_amdgcn_global_load_lds(GPTR(gA3), LPTR(A + 12288 + ldsoff), 16, 0, 0);
        __builtin_amdgcn_global_load_lds(GPTR(gB0), LPTR(B +     0 + ldsoff), 16, 0, 0);
        __builtin_amdgcn_global_load_lds(GPTR(gB1), LPTR(B +  4096 + ldsoff), 16, 0, 0);
        __builtin_amdgcn_global_load_lds(GPTR(gB2), LPTR(B +  8192 + ldsoff), 16, 0, 0);
        __builtin_amdgcn_global_load_lds(GPTR(gB3), LPTR(B + 12288 + ldsoff), 16, 0, 0);
    }

    for (int t = 0; t < BMU_NT; ++t) {
        // drain stage(t) (issued a full iteration ago), publish tile t
        asm volatile("s_waitcnt vmcnt(0)" ::: "memory");
        __builtin_amdgcn_s_barrier();
        asm volatile("" ::: "memory");   // no LDS-read hoisting above the barrier

        const _Float16* A = &AB[t & 1][0][0];
        const _Float16* B = &AB[t & 1][1][0];
        const bool more = (t + 1) < BMU_NT;
        _Float16* An = &AB[(t + 1) & 1][0][0];
        _Float16* Bn = &AB[(t + 1) & 1][1][0];
        const int tk = (t + 1) * 64;

        half8 af[8], bf[4];
        // ======== k-half h=0 (ck = q) ========
        #pragma unroll
        for (int i = 0; i < 4; ++i) af[i] = *(const half8*)(A + aoff[i]);
        bf[0] = *(const half8*)(B + boff[0]);
        bf[1] = *(const half8*)(B + boff[1]);
        if (more) __builtin_amdgcn_global_load_lds(GPTR(gA0 + tk), LPTR(An + 0 + ldsoff), 16, 0, 0);
        __builtin_amdgcn_s_setprio(1);
        #pragma unroll
        for (int i = 0; i < 4; ++i) {
            acc[i][0] = __builtin_amdgcn_mfma_f32_16x16x32_f16(af[i], bf[0], acc[i][0], 0, 0, 0);
            acc[i][1] = __builtin_amdgcn_mfma_f32_16x16x32_f16(af[i], bf[1], acc[i][1], 0, 0, 0);
        }
        __builtin_amdgcn_s_setprio(0);
        #pragma unroll
        for (int i = 4; i < 8; ++i) af[i] = *(const half8*)(A + aoff[i]);
        if (more) __builtin_amdgcn_global_load_lds(GPTR(gA1 + tk), LPTR(An + 4096 + ldsoff), 16, 0, 0);
        __builtin_amdgcn_s_setprio(1);
        #pragma unroll
        for (int i = 4; i < 8; ++i) {
            acc[i][0] = __builtin_amdgcn_mfma_f32_16x16x32_f16(af[i], bf[0], acc[i][0], 0, 0, 0);
            acc[i][1] = __builtin_amdgcn_mfma_f32_16x16x32_f16(af[i], bf[1], acc[i][1], 0, 0, 0);
        }
        __builtin_amdgcn_s_setprio(0);
        bf[2] = *(const half8*)(B + boff[2]);
        bf[3] = *(const half8*)(B + boff[3]);
        if (more) __builtin_amdgcn_global_load_lds(GPTR(gA2 + tk), LPTR(An + 8192 + ldsoff), 16, 0, 0);
        __builtin_amdgcn_s_setprio(1);
        #pragma unroll
        for (int i = 4; i < 8; ++i) {
            acc[i][2] = __builtin_amdgcn_mfma_f32_16x16x32_f16(af[i], bf[2], acc[i][2], 0, 0, 0);
            acc[i][3] = __builtin_amdgcn_mfma_f32_16x16x32_f16(af[i], bf[3], acc[i][3], 0, 0, 0);
        }
        __builtin_amdgcn_s_setprio(0);
        if (more) __builtin_amdgcn_global_load_lds(GPTR(gA3 + tk), LPTR(An + 12288 + ldsoff), 16, 0, 0);
        __builtin_amdgcn_s_setprio(1);
        #pragma unroll
        for (int i = 0; i < 4; ++i) {
            acc[i][2] = __builtin_amdgcn_mfma_f32_16x16x32_f16(af[i], bf[2], acc[i][2], 0, 0, 0);
            acc[i][3] = __builtin_amdgcn_mfma_f32_16x16x32_f16(af[i], bf[3], acc[i][3], 0, 0, 0);
        }
        __builtin_amdgcn_s_setprio(0);
        // ======== k-half h=1 (ck = 4+q; offset ^32) ========
        #pragma unroll
        for (int i = 0; i < 4; ++i) af[i] = *(const half8*)(A + (aoff[i] ^ 32));
        bf[0] = *(const half8*)(B + (boff[0] ^ 32));
        bf[1] = *(const half8*)(B + (boff[1] ^ 32));
        if (more) __builtin_amdgcn_global_load_lds(GPTR(gB0 + tk), LPTR(Bn + 0 + ldsoff), 16, 0, 0);
        __builtin_amdgcn_s_setprio(1);
        #pragma unroll
        for (int i = 0; i < 4; ++i) {
            acc[i][0] = __builtin_amdgcn_mfma_f32_16x16x32_f16(af[i], bf[0], acc[i][0], 0, 0, 0);
            acc[i][1] = __builtin_amdgcn_mfma_f32_16x16x32_f16(af[i], bf[1], acc[i][1], 0, 0, 0);
        }
        __builtin_amdgcn_s_setprio(0);
        #pragma unroll
        for (int i = 4; i < 8; ++i) af[i] = *(const half8*)(A + (aoff[i] ^ 32));
        if (more) __builtin_amdgcn_global_load_lds(GPTR(gB1 + tk), LPTR(Bn + 4096 + ldsoff), 16, 0, 0);
        __builtin_amdgcn_s_setprio(1);
        #pragma unroll
        for (int i = 4; i < 8; ++i) {
            acc[i][0] = __builtin_amdgcn_mfma_f32_16x16x32_f16(af[i], bf[0], acc[i][0], 0, 0, 0);
            acc[i][1] = __builtin_amdgcn_mfma_f32_16x16x32_f16(af[i], bf[1], acc[i][1], 0, 0, 0);
        }
        __builtin_amdgcn_s_setprio(0);
        bf[2] = *(const half8*)(B + (boff[2] ^ 32));
        bf[3] = *(const half8*)(B + (boff[3] ^ 32));
        if (more) __builtin_amdgcn_global_load_lds(GPTR(gB2 + tk), LPTR(Bn + 8192 + ldsoff), 16, 0, 0);
        __builtin_amdgcn_s_setprio(1);
        #pragma unroll
        for (int i = 4; i < 8; ++i) {
            acc[i][2] = __builtin_amdgcn_mfma_f32_16x16x32_f16(af[i], bf[2], acc[i][2], 0, 0, 0);
            acc[i][3] = __builtin_amdgcn_mfma_f32_16x16x32_f16(af[i], bf[3], acc[i][3], 0, 0, 0);
        }
        __builtin_amdgcn_s_setprio(0);
        if (more) __builtin_amdgcn_global_load_lds(GPTR(gB3 + tk), LPTR(Bn + 12288 + ldsoff), 16, 0, 0);
        __builtin_amdgcn_s_setprio(1);
        #pragma unroll
        for (int i = 0; i < 4; ++i) {
            acc[i][2] = __builtin_amdgcn_mfma_f32_16x16x32_f16(af[i], bf[2], acc[i][2], 0, 0, 0);
            acc[i][3] = __builtin_amdgcn_mfma_f32_16x16x32_f16(af[i], bf[3], acc[i][3], 0, 0, 0);
        }
        __builtin_amdgcn_s_setprio(0);
    }

    // ---------------- argmax epilogue (unchanged) ----------------
    float wnj[4];
    #pragma unroll
    for (int jj = 0; jj < 4; ++jj) wnj[jj] = wn2[c0 + wc * 64 + jj * 16 + l15];

    #pragma unroll
    for (int i = 0; i < 8; ++i) {
        #pragma unroll
        for (int r = 0; r < 4; ++r) {
            unsigned long long m = 0ULL;
            #pragma unroll
            for (int jj = 0; jj < 4; ++jj) {
                const float s = acc[i][jj][r] - wnj[jj];
                const unsigned long long p = packScore(s, c0 + wc * 64 + jj * 16 + l15);
                if (p > m) m = p;
            }
            #pragma unroll
            for (int msk = 1; msk <= 8; msk <<= 1) {
                const unsigned long long o = shfl_xor_u64(m, msk);
                if (o > m) m = o;
            }
            if (l15 == 0)
                atomicMax(&red[wr * 128 + i * 16 + q * 4 + r], m);
        }
    }
    __syncthreads();
    if (tid < 256) atomicMax(&best[b0 + tid], red[tid]);
}

// ---------------- scatter x rows into fp16 G (packed half2 atomics) + histogram ----------------
// Reads the ORIGINAL fp32 x (not xh: xh is inside G's footprint and zeroed).
__global__ void scatter_kernel(const unsigned long long* __restrict__ best,
                               const float* __restrict__ x,
                               _Float16* __restrict__ Gh, float* __restrict__ cnt) {
    const int b = blockIdx.x;
    const int c = (int)(~(unsigned)(best[b] & 0xFFFFFFFFULL));
    _Float16* gr = Gh + (size_t)c * DIM;
    const float2* xr = (const float2*)(x + (size_t)b * DIM);
    #pragma unroll
    for (int u = 0; u < 2; ++u) {
        const int d = threadIdx.x + u * 192;   // 384 half2 = 768 halves
        const float2 v = xr[d];
        half2v h;
        h[0] = (_Float16)v.x; h[1] = (_Float16)v.y;
        atomicAddPkF16(gr + d * 2, h);         // global_atomic_pk_add_f16
    }
    if (threadIdx.x == 0) atomicAdd(&cnt[c], 1.0f);
}

#define EP 136   // Es pitch (halves)
#define BP 40    // Bs pitch (halves)
// Bs write conflict fix: writes put rows d=8k+u at a fixed col -> bank
// (20u + col/2) is k-independent = 16-way conflict; octet-preserving col
// swizzle: store col' = col ^ ((k&3)<<3) -> 4-way writes; reads use
// q' = q ^ ((row>>3)&3), still exactly 2 lanes/bank (free).

// ---- conv pass A (MFMA): H[(i,jc), d] = sum_j E[jc,j] * G[(i,j), d]; fp16 G, H in-place ----
__global__ __launch_bounds__(256) void convA_kernel(
    const _Float16* Gh, _Float16* Hh, const int* __restrict__ itp) {
    __shared__ _Float16 Es[128 * EP];   // E fp16, later reused as fp32 bounce
    __shared__ _Float16 Bs[128 * BP];
    const int d0 = blockIdx.x * 128;    // 0..5
    const int ib = blockIdx.y;          // 0..127
    const int tid = threadIdx.x;
    const int wv = tid >> 6, lane = tid & 63;
    const int l15 = lane & 15, q = lane >> 4;
    const int mrow = (wv >> 1) * 64, ncol = (wv & 1) * 64;

    {   // compute E tile in LDS on the fly
        const float decay = 1.f - (float)(*itp) / NITER_F;
        const float sig = SIGMA0 * decay;
        const float inv = -1.f / (sig * sig);
        const int row = tid >> 1, hh = tid & 1;
        _Float16* dst = Es + row * EP + hh * 64;
        #pragma unroll
        for (int u = 0; u < 64; ++u) {
            const float dd = (float)(row - hh * 64 - u);
            dst[u] = (_Float16)__expf(dd * dd * inv);
        }
    }

    floatx4 acc[4][4];
    #pragma unroll
    for (int i = 0; i < 4; ++i)
        #pragma unroll
        for (int j = 0; j < 4; ++j) acc[i][j] = (floatx4){0.f, 0.f, 0.f, 0.f};

    const int dpo = (tid & 15) * 8;     // d-octet within 128
    const int rsel = tid >> 4;          // 0..15 row selector
    const int wsw = ((tid & 15) & 3) << 3;   // write col-swizzle = (k&3)<<3
    for (int k0 = 0; k0 < 128; k0 += 32) {
        __syncthreads();
        #pragma unroll
        for (int s = 0; s < 2; ++s) {   // coalesced: 16 lanes read one row's 256B
            const int j = k0 + s * 16 + rsel;
            const half8 v = *(const half8*)(Gh + (size_t)(ib * 128 + j) * DIM + d0 + dpo);
            #pragma unroll
            for (int u = 0; u < 8; ++u)
                Bs[(dpo + u) * BP + ((s * 16 + rsel) ^ wsw)] = v[u];
        }
        __syncthreads();
        half8 af[4], bf[4];
        #pragma unroll
        for (int i = 0; i < 4; ++i)
            af[i] = *(const half8*)(Es + (mrow + i * 16 + l15) * EP + k0 + q * 8);
        #pragma unroll
        for (int j = 0; j < 4; ++j) {
            const int row = ncol + j * 16 + l15;
            bf[j] = *(const half8*)(Bs + row * BP + ((q ^ ((row >> 3) & 3)) << 3));
        }
        #pragma unroll
        for (int i = 0; i < 4; ++i)
            #pragma unroll
            for (int j = 0; j < 4; ++j)
                acc[i][j] = __builtin_amdgcn_mfma_f32_16x16x32_f16(af[i], bf[j], acc[i][j], 0, 0, 0);
    }
    __syncthreads();
    // fp32 bounce epilogue in 2 chunks of 64 rows (m = jc); H fp16 natural
    // layout, in-place over G (this block's exact read range, reads done).
    float* Ebf = (float*)Es;            // [64][132] floats = 33792 B <= 34816
    #pragma unroll
    for (int ch = 0; ch < 2; ++ch) {
        if ((wv >> 1) == ch) {
            #pragma unroll
            for (int i = 0; i < 4; ++i)
                #pragma unroll
                for (int j = 0; j < 4; ++j)
                    #pragma unroll
                    for (int r = 0; r < 4; ++r)
                        Ebf[(i * 16 + q * 4 + r) * 132 + ncol + j * 16 + l15] = acc[i][j][r];
        }
        __syncthreads();
        {
            const int row = tid >> 2, seg = tid & 3;    // 64 rows x 4 segs of 32
            const int m = ch * 64 + row;                // jc
            _Float16* hp = Hh + (size_t)(ib * 128 + m) * DIM + d0 + seg * 32;
            #pragma unroll
            for (int u = 0; u < 4; ++u) {
                const float* sp = Ebf + row * 132 + seg * 32 + u * 8;
                half8 hv;
                #pragma unroll
                for (int e = 0; e < 8; ++e) hv[e] = (_Float16)sp[e];
                *(half8*)(hp + u * 8) = hv;
            }
        }
        __syncthreads();
    }
}

// ---- conv pass B (MFMA) + fused S-conv + epilogue:
//      out[(ic,jc),d] = w*(1-a*S[ic,jc]) + a * sum_i E[ic,i] H[(i,jc),d]
__global__ __launch_bounds__(256) void convB_kernel(
    const _Float16* Hh, const float* __restrict__ w, const float* __restrict__ cnt,
    const int* __restrict__ itp, float* __restrict__ out) {
    __shared__ _Float16 Es[128 * EP];
    __shared__ _Float16 Bs[128 * BP];
    __shared__ float cntHs[128];
    __shared__ float Ss[128];
    const int d0 = blockIdx.x * 128;    // 0..5
    const int jc = blockIdx.y;          // 0..127
    const int tid = threadIdx.x;
    const int wv = tid >> 6, lane = tid & 63;
    const int l15 = lane & 15, q = lane >> 4;
    const int mrow = (wv >> 1) * 64, ncol = (wv & 1) * 64;
    const float decay = 1.f - (float)(*itp) / NITER_F;
    const float alpha = ALPHA0 * decay;
    const float sig = SIGMA0 * decay;
    const float inv = -1.f / (sig * sig);

    // count-conv for this jc column (S[ic] for all ic), fp32
    if (tid < 128) {
        float s = 0.f;
        for (int j = 0; j < 128; ++j) {
            const float dd = (float)(jc - j);
            s += __expf(dd * dd * inv) * cnt[tid * 128 + j];
        }
        cntHs[tid] = s;
    }
    {   // compute E tile in LDS
        const int row = tid >> 1, hh = tid & 1;
        _Float16* dst = Es + row * EP + hh * 64;
        #pragma unroll
        for (int u = 0; u < 64; ++u) {
            const float dd = (float)(row - hh * 64 - u);
            dst[u] = (_Float16)__expf(dd * dd * inv);
        }
    }
    __syncthreads();
    if (tid < 128) {
        float s = 0.f;
        for (int i = 0; i < 128; ++i) {
            const float dd = (float)(tid - i);
            s += __expf(dd * dd * inv) * cntHs[i];
        }
        Ss[tid] = s;
    }

    floatx4 acc[4][4];
    #pragma unroll
    for (int i = 0; i < 4; ++i)
        #pragma unroll
        for (int j = 0; j < 4; ++j) acc[i][j] = (floatx4){0.f, 0.f, 0.f, 0.f};

    const int dpo = (tid & 15) * 8;
    const int rsel = tid >> 4;
    const int wsw = ((tid & 15) & 3) << 3;
    for (int k0 = 0; k0 < 128; k0 += 32) {
        __syncthreads();
        #pragma unroll
        for (int s = 0; s < 2; ++s) {   // coalesced: 16 lanes read one row's 256B chunk
            const int i = k0 + s * 16 + rsel;
            const half8 v = *(const half8*)(Hh + (size_t)(i * 128 + jc) * DIM + d0 + dpo);
            #pragma unroll
            for (int u = 0; u < 8; ++u)
                Bs[(dpo + u) * BP + ((s * 16 + rsel) ^ wsw)] = v[u];
        }
        __syncthreads();
        half8 af[4], bf[4];
        #pragma unroll
        for (int i = 0; i < 4; ++i)
            af[i] = *(const half8*)(Es + (mrow + i * 16 + l15) * EP + k0 + q * 8);
        #pragma unroll
        for (int j = 0; j < 4; ++j) {
            const int row = ncol + j * 16 + l15;
            bf[j] = *(const half8*)(Bs + row * BP + ((q ^ ((row >> 3) & 3)) << 3));
        }
        #pragma unroll
        for (int i = 0; i < 4; ++i)
            #pragma unroll
            for (int j = 0; j < 4; ++j)
                acc[i][j] = __builtin_amdgcn_mfma_f32_16x16x32_f16(af[i], bf[j], acc[i][j], 0, 0, 0);
    }
    __syncthreads();
    // fused epilogue: fp32 bounce in 2 chunks of 64 rows (m = ic)
    float* Ebf = (float*)Es;            // [64][132] floats
    #pragma unroll
    for (int ch = 0; ch < 2; ++ch) {
        if ((wv >> 1) == ch) {
            #pragma unroll
            for (int i = 0; i < 4; ++i)
                #pragma unroll
                for (int j = 0; j < 4; ++j)
                    #pragma unroll
                    for (int r = 0; r < 4; ++r)
                        Ebf[(i * 16 + q * 4 + r) * 132 + ncol + j * 16 + l15] = acc[i][j][r];
        }
        __syncthreads();
        {
            const int row = tid >> 2, seg = tid & 3;    // 64 rows x 4 segs of 32 floats
            const int m = ch * 64 + row;                // ic
            const int c = m * 128 + jc;
            const float scl = 1.f - alpha * Ss[m];
            const size_t g = (size_t)c * DIM + d0 + seg * 32;
            #pragma unroll
            for (int u = 0; u < 8; ++u) {
                float4 wv4 = *(const float4*)(w + g + u * 4);
                float4 t4  = *(const float4*)(Ebf + row * 132 + seg * 32 + u * 4);
                float4 o;
                o.x = wv4.x * scl + alpha * t4.x;
                o.y = wv4.y * scl + alpha * t4.y;
                o.z = wv4.z * scl + alpha * t4.z;
                o.w = wv4.w * scl + alpha * t4.w;
                *(float4*)(out + g + u * 4) = o;
            }
        }
        __syncthreads();
    }
}

extern "C" void kernel_launch(void* const* d_in, const int* in_sizes, int n_in,
                              void* d_out, int out_size, void* d_ws, size_t ws_size,
                              hipStream_t stream) {
    const float* x  = (const float*)d_in[0];   // [4096, 768]
    const float* w  = (const float*)d_in[1];   // [16384, 768]
    const int* itp  = (const int*)d_in[2];     // scalar it
    float* out = (float*)d_out;                // [16384, 768]
    char* ws = (char*)d_ws;

    _Float16* xh = (_Float16*)(ws + XH_OFF);
    _Float16* wh = (_Float16*)(ws + WH_OFF);
    _Float16* Gh = (_Float16*)(ws + G_OFF);    // fp16 G, aliases xh/wh post-bmu
    unsigned long long* best = (unsigned long long*)(ws + BEST_OFF);
    float* cnt  = (float*)(ws + CNT_OFF);
    float* wn2  = (float*)(ws + WN2_OFF);

    // best/cnt zeroing folded into cvt_kernel (one fewer launch)
    cvt_kernel<<<(BS * DIM / 4 + 255) / 256, 256, 0, stream>>>(x, xh, BS * DIM / 4, best, cnt);
    cvtw_wn2_kernel<<<COMPS, 192, 0, stream>>>(w, wh, wn2);

    // 1024 blocks = 16 b-tiles x 64 c-tiles (XCD-remapped inside the kernel)
    bmu_kernel<<<dim3(1024), 512, 0, stream>>>(xh, wh, wn2, best);

    // xh/wh dead -> zero fp16 G (stream-ordered after bmu)
    hipMemsetAsync(ws + G_OFF, 0, GH_BYTES, stream);
    scatter_kernel<<<BS, 192, 0, stream>>>(best, x, Gh, cnt);

    // pass A: conv along j, H fp16 written in-place over G
    convA_kernel<<<dim3(6, 128), 256, 0, stream>>>(Gh, Gh, itp);
    // pass B + count-conv + epilogue -> d_out
    convB_kernel<<<dim3(6, 128), 256, 0, stream>>>(Gh, w, cnt, itp, out);
}